// Round 1
// baseline (896.146 us; speedup 1.0000x reference)
//
#include <hip/hip_runtime.h>
#include <math.h>

typedef __attribute__((ext_vector_type(8))) short short8;
typedef __attribute__((ext_vector_type(4))) float f32x4;

#define BB 2
#define TT 6
#define PP 20480
#define DIMX 96
#define DSTAT 8
#define INH 28
#define EMBH 32
#define DIN 128
#define NHh 8
#define CONVD 130
#define DPROJ 266
#define LSEQ 30
#define EPSc 1e-5f

// ws layout (bytes), all 16B aligned
#define WS_WIN   0u           // in_proj frags  [17][4][64] short8 = 69632
#define WS_WOUT  69632u       // out_proj frags [6][4][64]  short8 = 24576
#define WS_W1    94208u       // mlp_w1 frags   [6][3][64]  short8 = 18432
#define WS_W2    112640u      // mlp_w2 frags   [6][3][64]  short8 = 18432
#define WS_XN    131072u      // xn bf16 [245760][128] = 62914560
#define WS_YF    63045632u    // y_f bf16 [B][T][P][128] = 62914560
#define WS_YB    125960192u   // y_b bf16 (pre-flipped dest) = 62914560
// total = 188874752 bytes

__device__ __forceinline__ float bf2f(unsigned int h){
  unsigned int u = h << 16; float f; __builtin_memcpy(&f, &u, 4); return f;
}
__device__ __forceinline__ unsigned short f2bf(float f){
  unsigned int u; __builtin_memcpy(&u, &f, 4);
  unsigned int r = (u + 0x7fffu + ((u >> 16) & 1u)) >> 16;
  return (unsigned short)r;
}
__device__ __forceinline__ float sigm(float x){ return 1.0f / (1.0f + __expf(-x)); }

// ---------------- K0: weight prep -> bf16 MFMA B-fragments ----------------
// frag(nt,kk,lane,j) = W[kk*32 + (lane>>4)*8 + j][nt*16 + (lane&15)]  (0 if n>=N)
__global__ __launch_bounds__(256) void k0_wprep(
    const float* __restrict__ win, const float* __restrict__ wout,
    const float* __restrict__ w1, const float* __restrict__ w2,
    unsigned char* __restrict__ ws)
{
  int gt = blockIdx.x * 256 + threadIdx.x;   // 8192 threads, 128 frag-groups
  int g = gt >> 6, lane = gt & 63;
  const float* src; int N; int gl; unsigned int dst;
  if (g < 68)       { src = win;  N = 266; gl = g;       dst = WS_WIN;  }
  else if (g < 92)  { src = wout; N = 96;  gl = g - 68;  dst = WS_WOUT; }
  else if (g < 110) { src = w1;   N = 96;  gl = g - 92;  dst = WS_W1;   }
  else              { src = w2;   N = 96;  gl = g - 110; dst = WS_W2;   }
  int kk, nt;
  if (g < 92) { nt = gl / 4; kk = gl % 4; } else { nt = gl / 3; kk = gl % 3; }
  int n = nt * 16 + (lane & 15);
  int k0 = kk * 32 + (lane >> 4) * 8;
  union { unsigned short u[8]; short8 s; } cv;
  #pragma unroll
  for (int j = 0; j < 8; j++){
    float f = (n < N) ? src[(size_t)(k0 + j) * N + n] : 0.0f;
    cv.u[j] = f2bf(f);
  }
  *(short8*)(ws + dst + (size_t)(gl * 64 + lane) * 16) = cv.s;
}

// ---------------- K1: gather + embed + LN + loan1 -> xn (bf16) ----------------
__global__ __launch_bounds__(256) void k1_prep(
    const float* __restrict__ x, const float* __restrict__ xst,
    const float* __restrict__ xhr, const int* __restrict__ curves,
    const float* __restrict__ ew, const float* __restrict__ eb,
    const float* __restrict__ l1w, const float* __restrict__ l1b,
    unsigned char* __restrict__ ws)
{
  int wid = threadIdx.x >> 6, lane = threadIdx.x & 63;
  int pos = blockIdx.x * 4 + wid;                 // < 245760
  int b = pos / (TT * PP); int r = pos % (TT * PP);
  int t = r / PP; int p = r % PP;
  int cp = curves[b * PP + p];
  size_t gbase = ((size_t)(b * TT + t) * PP + cp);
  const float* xrow  = x   + gbase * DIMX;
  const float* xhrow = xhr + gbase * INH;
  const float* xsrow = xst + gbase * DSTAT;

  float v0 = xrow[lane];     // xc[lane]  (lane<64<96 -> always x part)
  float v1;
  if (lane < 32) v1 = xrow[64 + lane];            // xc[lane+64], still x part
  else {
    int e = lane - 32;                            // hr[e]
    float acc = eb[e];
    #pragma unroll
    for (int d = 0; d < INH; d++) acc += xhrow[d] * ew[d * EMBH + e];
    v1 = tanhf(acc);
  }
  // LayerNorm over 128 (no affine)
  float s = v0 + v1, q = v0 * v0 + v1 * v1;
  #pragma unroll
  for (int m = 1; m < 64; m <<= 1){ s += __shfl_xor(s, m); q += __shfl_xor(q, m); }
  float mu = s * (1.0f / 128.0f);
  float var = q * (1.0f / 128.0f) - mu * mu;
  float rs = rsqrtf(var + EPSc);
  // + tanh(xs @ loan1 + b)
  float a0 = l1b[lane], a1 = l1b[64 + lane];
  #pragma unroll
  for (int d = 0; d < DSTAT; d++){
    float xv = xsrow[d];
    a0 += xv * l1w[d * DIN + lane];
    a1 += xv * l1w[d * DIN + 64 + lane];
  }
  float xn0 = (v0 - mu) * rs + tanhf(a0);
  float xn1 = (v1 - mu) * rs + tanhf(a1);
  unsigned short* dst = (unsigned short*)(ws + WS_XN) + (size_t)pos * 128;
  dst[lane]      = f2bf(xn0);
  dst[64 + lane] = f2bf(xn1);
}

// ---------------- K2: fused in_proj MFMA + bidirectional Mamba scan ----------------
// block = (b, tb, pb): handles fwd seq (b,tb,pb) and bwd seq (b,tb,2047-pb),
// which read the SAME 30 u-cells (t=3tb+g0, p=10pb+g1). u lives in LDS only.
__global__ __launch_bounds__(128) void k2_mamba(
    unsigned char* __restrict__ ws,
    const float* __restrict__ cwf, const float* __restrict__ cbf,
    const float* __restrict__ dtbf, const float* __restrict__ alf,
    const float* __restrict__ Dpf, const float* __restrict__ nwf,
    const float* __restrict__ cwb, const float* __restrict__ cbb,
    const float* __restrict__ dtbb, const float* __restrict__ alb,
    const float* __restrict__ Dpb, const float* __restrict__ nwb)
{
  __shared__ unsigned short uld[30][272];   // u tile, bf16, cols 0..265 valid
  int blk = blockIdx.x;
  int pb = blk & 2047; int tb = (blk >> 11) & 1; int b = blk >> 12;
  int wid = threadIdx.x >> 6, lane = threadIdx.x & 63;

  // --- phase 1: u = xn @ W_in via MFMA (wave w computes rows 16w..16w+15) ---
  const unsigned short* xn = (const unsigned short*)(ws + WS_XN);
  f32x4 acc[17];
  #pragma unroll
  for (int i = 0; i < 17; i++) acc[i] = (f32x4){0.f,0.f,0.f,0.f};
  int lr = wid * 16 + (lane & 15); if (lr > 29) lr = 29;   // pad rows clamp
  int g0 = lr / 10, g1 = lr % 10;
  size_t posA = ((size_t)(b * TT + tb * 3 + g0) * PP + (size_t)pb * 10 + g1);
  const unsigned short* arow = xn + posA * 128 + (lane >> 4) * 8;
  const short8* bb = (const short8*)(ws + WS_WIN);
  #pragma unroll
  for (int kk = 0; kk < 4; kk++){
    short8 af = *(const short8*)(arow + kk * 32);
    #pragma unroll
    for (int nt = 0; nt < 17; nt++){
      short8 bf = bb[(nt * 4 + kk) * 64 + lane];
      acc[nt] = __builtin_amdgcn_mfma_f32_16x16x32_bf16(af, bf, acc[nt], 0, 0, 0);
    }
  }
  {
    int row0 = wid * 16 + (lane >> 4) * 4;
    int col0 = lane & 15;
    #pragma unroll
    for (int nt = 0; nt < 17; nt++){
      #pragma unroll
      for (int r2 = 0; r2 < 4; r2++){
        int row = row0 + r2, col = nt * 16 + col0;
        if (row < 30 && col < 266) uld[row][col] = f2bf(acc[nt][r2]);
      }
    }
  }
  __syncthreads();

  // --- phase 2: scan. wave0 = fwd, wave1 = bwd ---
  const float* cw  = wid ? cwb  : cwf;
  const float* cb  = wid ? cbb  : cbf;
  const float* dtb = wid ? dtbb : dtbf;
  const float* al  = wid ? alb  : alf;
  const float* Dp  = wid ? Dpb  : Dpf;
  const float* nw  = wid ? nwb  : nwf;
  unsigned int* ybuf = (unsigned int*)(ws + (wid ? WS_YB : WS_YF));
  int pbown = wid ? (2047 - pb) : pb;

  int c0 = lane * 2, c1 = c0 + 1;
  int hh = lane >> 3;
  float w00=cw[c0*3+0], w01=cw[c0*3+1], w02=cw[c0*3+2], cb0=cb[c0];
  float w10=cw[c1*3+0], w11=cw[c1*3+1], w12=cw[c1*3+2], cb1=cb[c1];
  float wB0=cw[128*3+0], wB1=cw[128*3+1], wB2=cw[128*3+2], cbB=cb[128];
  float wC0=cw[129*3+0], wC1=cw[129*3+1], wC2=cw[129*3+2], cbC=cb[129];
  float Ah = -__expf(al[hh]);
  float dtbh = dtb[hh], Dh = Dp[hh];
  float nw0 = nw[c0], nw1 = nw[c1];

  float xp10=0,xp20=0,xp11=0,xp21=0, Bp1=0,Bp2=0, Cp1=0,Cp2=0;
  float h0=0.f, h1=0.f;
  for (int l = 0; l < 30; l++){
    int gg0 = l / 10, gg1 = l % 10;
    int urow = wid ? (gg0 * 10 + (9 - gg1)) : l;   // bwd reads reversed cells
    const unsigned short* ur = &uld[urow][0];
    unsigned int zz = *(const unsigned int*)(ur + c0);
    unsigned int xx = *(const unsigned int*)(ur + 128 + c0);
    unsigned int bc = *(const unsigned int*)(ur + 256);
    float z0 = bf2f(zz & 0xffff), z1 = bf2f(zz >> 16);
    float xr0 = bf2f(xx & 0xffff), xr1 = bf2f(xx >> 16);
    float Br = bf2f(bc & 0xffff), Cr = bf2f(bc >> 16);
    float dtr = bf2f(ur[258 + hh]);
    // causal conv (taps at l-2,l-1,l) + bias
    float xc0 = w00*xp20 + w01*xp10 + w02*xr0 + cb0;
    float xc1 = w10*xp21 + w11*xp11 + w12*xr1 + cb1;
    float Bc  = wB0*Bp2 + wB1*Bp1 + wB2*Br + cbB;
    float Cc  = wC0*Cp2 + wC1*Cp1 + wC2*Cr + cbC;
    xp20=xp10; xp10=xr0; xp21=xp11; xp11=xr1;
    Bp2=Bp1; Bp1=Br; Cp2=Cp1; Cp1=Cr;
    float xh0 = xc0 * sigm(xc0), xh1 = xc1 * sigm(xc1);
    float Bv = Bc * sigm(Bc), Cv = Cc * sigm(Cc);
    float dtx = dtr + dtbh;
    float dt = fmaxf(dtx, 0.0f) + log1pf(__expf(-fabsf(dtx)));   // softplus
    float dA = __expf(dt * Ah);
    float sB = dt * Bv;
    h0 = h0 * dA + xh0 * sB;
    h1 = h1 * dA + xh1 * sB;
    float y0 = h0 * Cv + xh0 * Dh;
    float y1 = h1 * Cv + xh1 * Dh;
    y0 *= z0 * sigm(z0);
    y1 *= z1 * sigm(z1);
    // RMSNorm over 128
    float ss = y0*y0 + y1*y1;
    #pragma unroll
    for (int m = 1; m < 64; m <<= 1) ss += __shfl_xor(ss, m);
    float rsv = rsqrtf(ss * (1.0f / 128.0f) + EPSc);
    y0 *= rsv * nw0;
    y1 *= rsv * nw1;
    // _wrev destination (exact reference mapping), bwd also flipped in p
    int R = tb * 61440 + pbown * 30 + l;
    int q1 = R / 60, rr = R % 60;
    int q2 = rr / 30, rr2 = rr % 30, q3 = rr2 / 3, q4 = rr2 % 3;
    int idx = q3 * 12288 + q1 * 6 + q4 * 2 + q2;
    int tD = idx / 20480, pD = idx % 20480;
    if (wid) pD = 20479 - pD;
    unsigned int pack = ((unsigned int)f2bf(y1) << 16) | (unsigned int)f2bf(y0);
    ybuf[((size_t)(b * TT + tD) * PP + pD) * 64 + lane] = pack;
  }
}

// ---------------- K3: fused epilogue ----------------
// y=0.5(yf+yb) -> x1 = xg + y@Wout -> LN + tanh(xs@loan2) -> gelu(.@W1+b1) -> .@W2+b2 + x1
__global__ __launch_bounds__(256) void k3_epi(
    const unsigned char* __restrict__ ws,
    const float* __restrict__ x, const float* __restrict__ xst,
    const int* __restrict__ curves,
    const float* __restrict__ l2w, const float* __restrict__ l2b,
    const float* __restrict__ b1, const float* __restrict__ b2,
    float* __restrict__ out)
{
  __shared__ unsigned short Abuf[64 * 128];   // swizzled bf16 A-tile (reused 3x)
  __shared__ float X1[64][100];               // x1 fp32 (padded stride)
  int tid = threadIdx.x; int lane = tid & 63; int w = tid >> 6;
  size_t pos0 = (size_t)blockIdx.x * 64;
  int b = (int)(pos0 / (TT * PP)); int rm = (int)(pos0 % (TT * PP));
  int t = rm / PP; int p0 = rm % PP;

  // stage 0: A1 = bf16(0.5*(yf+yb)), XOR-swizzled rows
  {
    const unsigned int* yf = (const unsigned int*)(ws + WS_YF) + pos0 * 64;
    const unsigned int* yb = (const unsigned int*)(ws + WS_YB) + pos0 * 64;
    for (int i = tid; i < 64 * 64; i += 256){
      int pr = i >> 6, cpair = i & 63;
      unsigned int a = yf[pr * 64 + cpair], c = yb[pr * 64 + cpair];
      float lo = 0.5f * (bf2f(a & 0xffff) + bf2f(c & 0xffff));
      float hi = 0.5f * (bf2f(a >> 16) + bf2f(c >> 16));
      unsigned int pk = ((unsigned int)f2bf(hi) << 16) | (unsigned int)f2bf(lo);
      int off = pr * 256 + ((cpair * 4) ^ ((pr & 7) << 5));
      *(unsigned int*)((unsigned char*)Abuf + off) = pk;
    }
  }
  __syncthreads();

  // stage 1: x1 = y @ W_out + xg
  f32x4 acc[6];
  #pragma unroll
  for (int i = 0; i < 6; i++) acc[i] = (f32x4){0.f,0.f,0.f,0.f};
  {
    int arow = w * 16 + (lane & 15);
    const short8* bbm = (const short8*)(ws + WS_WOUT);
    #pragma unroll
    for (int kk = 0; kk < 4; kk++){
      int off = arow * 256 + ((kk * 64 + (lane >> 4) * 16) ^ ((arow & 7) << 5));
      short8 af = *(const short8*)((const unsigned char*)Abuf + off);
      #pragma unroll
      for (int nt = 0; nt < 6; nt++){
        short8 bf = bbm[(nt * 4 + kk) * 64 + lane];
        acc[nt] = __builtin_amdgcn_mfma_f32_16x16x32_bf16(af, bf, acc[nt], 0, 0, 0);
      }
    }
    int row0 = w * 16 + (lane >> 4) * 4;
    int col = lane & 15;
    const int* cur = curves + b * PP;
    #pragma unroll
    for (int r2 = 0; r2 < 4; r2++){
      int row = row0 + r2;
      int cp = cur[p0 + row];
      const float* xr = x + ((size_t)(b * TT + t) * PP + cp) * 96;
      #pragma unroll
      for (int nt = 0; nt < 6; nt++){
        int n = nt * 16 + col;
        X1[row][n] = acc[nt][r2] + xr[n];
      }
    }
  }
  __syncthreads();

  // stage 2: t1 = LN(x1) + tanh(xs @ loan2 + l2b) -> A2 (bf16 swizzled)
  {
    int pr = tid >> 2, qq = tid & 3;
    float s = 0.f, ssq = 0.f;
    #pragma unroll
    for (int j = 0; j < 24; j++){ float v = X1[pr][qq * 24 + j]; s += v; ssq += v * v; }
    s += __shfl_xor(s, 1); ssq += __shfl_xor(ssq, 1);
    s += __shfl_xor(s, 2); ssq += __shfl_xor(ssq, 2);
    float mu = s * (1.0f / 96.0f);
    float rsv = rsqrtf(ssq * (1.0f / 96.0f) - mu * mu + EPSc);
    int cp = curves[b * PP + p0 + pr];
    const float* xsr = xst + ((size_t)(b * TT + t) * PP + cp) * 8;
    float xsv[8];
    #pragma unroll
    for (int d = 0; d < 8; d++) xsv[d] = xsr[d];
    for (int j = 0; j < 24; j++){
      int cch = qq * 24 + j;
      float a = l2b[cch];
      #pragma unroll
      for (int d = 0; d < 8; d++) a += xsv[d] * l2w[d * 96 + cch];
      float t1 = (X1[pr][cch] - mu) * rsv + tanhf(a);
      int off = pr * 256 + ((cch * 2) ^ ((pr & 7) << 5));
      *(unsigned short*)((unsigned char*)Abuf + off) = f2bf(t1);
    }
  }
  __syncthreads();

  // stage 3: m = t1 @ W1 + b1 -> gelu -> A3
  f32x4 acc2[6];
  #pragma unroll
  for (int i = 0; i < 6; i++) acc2[i] = (f32x4){0.f,0.f,0.f,0.f};
  {
    int arow = w * 16 + (lane & 15);
    const short8* bbm = (const short8*)(ws + WS_W1);
    #pragma unroll
    for (int kk = 0; kk < 3; kk++){
      int off = arow * 256 + ((kk * 64 + (lane >> 4) * 16) ^ ((arow & 7) << 5));
      short8 af = *(const short8*)((const unsigned char*)Abuf + off);
      #pragma unroll
      for (int nt = 0; nt < 6; nt++){
        short8 bf = bbm[(nt * 3 + kk) * 64 + lane];
        acc2[nt] = __builtin_amdgcn_mfma_f32_16x16x32_bf16(af, bf, acc2[nt], 0, 0, 0);
      }
    }
  }
  __syncthreads();   // everyone done reading A2 before overwrite
  {
    int row0 = w * 16 + (lane >> 4) * 4;
    int col = lane & 15;
    #pragma unroll
    for (int nt = 0; nt < 6; nt++){
      int n = nt * 16 + col;
      float bv = b1[n];
      #pragma unroll
      for (int r2 = 0; r2 < 4; r2++){
        float v = acc2[nt][r2] + bv;
        float g = 0.5f * v * (1.0f + erff(v * 0.70710678118654752f));
        int row = row0 + r2;
        int off = row * 256 + ((n * 2) ^ ((row & 7) << 5));
        *(unsigned short*)((unsigned char*)Abuf + off) = f2bf(g);
      }
    }
  }
  __syncthreads();

  // stage 4: out = gelu @ W2 + b2 + x1
  f32x4 acc3[6];
  #pragma unroll
  for (int i = 0; i < 6; i++) acc3[i] = (f32x4){0.f,0.f,0.f,0.f};
  {
    int arow = w * 16 + (lane & 15);
    const short8* bbm = (const short8*)(ws + WS_W2);
    #pragma unroll
    for (int kk = 0; kk < 3; kk++){
      int off = arow * 256 + ((kk * 64 + (lane >> 4) * 16) ^ ((arow & 7) << 5));
      short8 af = *(const short8*)((const unsigned char*)Abuf + off);
      #pragma unroll
      for (int nt = 0; nt < 6; nt++){
        short8 bf = bbm[(nt * 3 + kk) * 64 + lane];
        acc3[nt] = __builtin_amdgcn_mfma_f32_16x16x32_bf16(af, bf, acc3[nt], 0, 0, 0);
      }
    }
    int row0 = w * 16 + (lane >> 4) * 4;
    int col = lane & 15;
    #pragma unroll
    for (int r2 = 0; r2 < 4; r2++){
      int row = row0 + r2;
      size_t obase = ((size_t)(b * TT + t) * PP + (p0 + row)) * 96;
      #pragma unroll
      for (int nt = 0; nt < 6; nt++){
        int n = nt * 16 + col;
        out[obase + n] = acc3[nt][r2] + b2[n] + X1[row][n];
      }
    }
  }
}

extern "C" void kernel_launch(void* const* d_in, const int* in_sizes, int n_in,
                              void* d_out, int out_size, void* d_ws, size_t ws_size,
                              hipStream_t stream)
{
  const float* x     = (const float*)d_in[0];
  const float* xst   = (const float*)d_in[1];
  const float* xhr   = (const float*)d_in[2];
  const int*   curves= (const int*)d_in[3];
  const float* embw  = (const float*)d_in[4];
  const float* embb  = (const float*)d_in[5];
  const float* l1w   = (const float*)d_in[6];
  const float* l1b   = (const float*)d_in[7];
  const float* l2w   = (const float*)d_in[8];
  const float* l2b   = (const float*)d_in[9];
  const float* winp  = (const float*)d_in[10];
  const float* cwf   = (const float*)d_in[11];
  const float* cbf   = (const float*)d_in[12];
  const float* dtbf  = (const float*)d_in[13];
  const float* alf   = (const float*)d_in[14];
  const float* Df    = (const float*)d_in[15];
  const float* nwf   = (const float*)d_in[16];
  const float* cwb   = (const float*)d_in[17];
  const float* cbb   = (const float*)d_in[18];
  const float* dtbb  = (const float*)d_in[19];
  const float* alb   = (const float*)d_in[20];
  const float* Db    = (const float*)d_in[21];
  const float* nwb   = (const float*)d_in[22];
  const float* wout  = (const float*)d_in[23];
  const float* w1    = (const float*)d_in[24];
  const float* b1    = (const float*)d_in[25];
  const float* w2    = (const float*)d_in[26];
  const float* b2    = (const float*)d_in[27];
  unsigned char* ws  = (unsigned char*)d_ws;

  k0_wprep<<<32, 256, 0, stream>>>(winp, wout, w1, w2, ws);
  k1_prep<<<61440, 256, 0, stream>>>(x, xst, xhr, curves, embw, embb, l1w, l1b, ws);
  k2_mamba<<<8192, 128, 0, stream>>>(ws, cwf, cbf, dtbf, alf, Df, nwf,
                                         cwb, cbb, dtbb, alb, Db, nwb);
  k3_epi<<<3840, 256, 0, stream>>>(ws, x, xst, curves, l2w, l2b, b1, b2, (float*)d_out);
}

// Round 3
// 632.495 us; speedup vs baseline: 1.4168x; 1.4168x over previous
//
#include <hip/hip_runtime.h>
#include <math.h>

typedef __attribute__((ext_vector_type(8))) short short8;
typedef __attribute__((ext_vector_type(4))) float f32x4;

#define BB 2
#define TT 6
#define PP 20480
#define DIMX 96
#define DSTAT 8
#define INH 28
#define EMBH 32
#define DIN 128
#define CONVD 130
#define DPROJ 266
#define EPSc 1e-5f

// ws layout (bytes), all 16B aligned
#define WS_WIN   0u           // in_proj frags  [17][4][64] short8 = 69632
#define WS_WOUT  69632u       // out_proj frags [6][4][64]  short8 = 24576
#define WS_W1    94208u       // mlp_w1 frags   [6][3][64]  short8 = 18432
#define WS_W2    112640u      // mlp_w2 frags   [6][3][64]  short8 = 18432
#define WS_XN    131072u      // xn bf16 [245760][128] = 62914560
#define WS_YF    63045632u    // y_f bf16 (pre-norm) [B][T][P][128] = 62914560
#define WS_YB    125960192u   // y_b bf16 (pre-norm, pre-flipped dest) = 62914560

__device__ __forceinline__ float asf(unsigned int u){ float f; __builtin_memcpy(&f, &u, 4); return f; }
__device__ __forceinline__ unsigned short f2bf(float f){
  unsigned int u; __builtin_memcpy(&u, &f, 4);
  unsigned int r = (u + 0x7fffu + ((u >> 16) & 1u)) >> 16;
  return (unsigned short)r;
}
__device__ __forceinline__ float fast_sigm(float x){ return __builtin_amdgcn_rcpf(1.0f + __expf(-x)); }
__device__ __forceinline__ float fast_tanh(float x){ return 1.0f - 2.0f * __builtin_amdgcn_rcpf(1.0f + __expf(2.0f * x)); }
__device__ __forceinline__ float fast_gelu(float v){
  // exact-erf gelu via A&S 7.1.26 rational approx (|err| ~1.5e-7)
  float s = v * 0.70710678118654752f;
  float ax = fabsf(s);
  float t = __builtin_amdgcn_rcpf(1.0f + 0.3275911f * ax);
  float p = t * (0.254829592f + t * (-0.284496736f + t * (1.421413741f + t * (-1.453152027f + t * 1.061405429f))));
  float er = 1.0f - p * __expf(-ax * ax);
  er = (s < 0.0f) ? -er : er;
  return 0.5f * v * (1.0f + er);
}

// ---------------- K0: weight prep -> bf16 MFMA B-fragments ----------------
__global__ __launch_bounds__(256) void k0_wprep(
    const float* __restrict__ win, const float* __restrict__ wout,
    const float* __restrict__ w1, const float* __restrict__ w2,
    unsigned char* __restrict__ ws)
{
  int gt = blockIdx.x * 256 + threadIdx.x;
  int g = gt >> 6, lane = gt & 63;
  const float* src; int N; int gl; unsigned int dst;
  if (g < 68)       { src = win;  N = 266; gl = g;       dst = WS_WIN;  }
  else if (g < 92)  { src = wout; N = 96;  gl = g - 68;  dst = WS_WOUT; }
  else if (g < 110) { src = w1;   N = 96;  gl = g - 92;  dst = WS_W1;   }
  else              { src = w2;   N = 96;  gl = g - 110; dst = WS_W2;   }
  int kk, nt;
  if (g < 92) { nt = gl / 4; kk = gl % 4; } else { nt = gl / 3; kk = gl % 3; }
  int n = nt * 16 + (lane & 15);
  int k0 = kk * 32 + (lane >> 4) * 8;
  union { unsigned short u[8]; short8 s; } cv;
  #pragma unroll
  for (int j = 0; j < 8; j++){
    float f = (n < N) ? src[(size_t)(k0 + j) * N + n] : 0.0f;
    cv.u[j] = f2bf(f);
  }
  *(short8*)(ws + dst + (size_t)(gl * 64 + lane) * 16) = cv.s;
}

// ---------------- K1: gather + embed + LN + loan1 -> xn (bf16) ----------------
__global__ __launch_bounds__(256) void k1_prep(
    const float* __restrict__ x, const float* __restrict__ xst,
    const float* __restrict__ xhr, const int* __restrict__ curves,
    const float* __restrict__ ew, const float* __restrict__ eb,
    const float* __restrict__ l1w, const float* __restrict__ l1b,
    unsigned char* __restrict__ ws)
{
  int wid = threadIdx.x >> 6, lane = threadIdx.x & 63;
  int pos = blockIdx.x * 4 + wid;
  int b = pos / (TT * PP); int r = pos % (TT * PP);
  int t = r / PP; int p = r % PP;
  int cp = curves[b * PP + p];
  size_t gbase = ((size_t)(b * TT + t) * PP + cp);
  const float* xrow  = x   + gbase * DIMX;
  const float* xhrow = xhr + gbase * INH;
  const float* xsrow = xst + gbase * DSTAT;

  float v0 = xrow[lane];
  float v1;
  if (lane < 32) v1 = xrow[64 + lane];
  else {
    int e = lane - 32;
    float acc = eb[e];
    #pragma unroll
    for (int d = 0; d < INH; d++) acc += xhrow[d] * ew[d * EMBH + e];
    v1 = fast_tanh(acc);
  }
  float s = v0 + v1, q = v0 * v0 + v1 * v1;
  #pragma unroll
  for (int m = 1; m < 64; m <<= 1){ s += __shfl_xor(s, m); q += __shfl_xor(q, m); }
  float mu = s * (1.0f / 128.0f);
  float var = q * (1.0f / 128.0f) - mu * mu;
  float rs = __builtin_amdgcn_rsqf(var + EPSc);
  float a0 = l1b[lane], a1 = l1b[64 + lane];
  #pragma unroll
  for (int d = 0; d < DSTAT; d++){
    float xv = xsrow[d];
    a0 += xv * l1w[d * DIN + lane];
    a1 += xv * l1w[d * DIN + 64 + lane];
  }
  float xn0 = (v0 - mu) * rs + fast_tanh(a0);
  float xn1 = (v1 - mu) * rs + fast_tanh(a1);
  unsigned short* dst = (unsigned short*)(ws + WS_XN) + (size_t)pos * 128;
  dst[lane]      = f2bf(xn0);
  dst[64 + lane] = f2bf(xn1);
}

// ---------------- K2: fused in_proj MFMA + bidirectional Mamba scan ----------------
// 256 threads = 4 waves = 2 window-pairs. pair = wid>>1, dir = wid&1.
// Stores y PRE-RMSNorm (norm deferred to K3).
__global__ __launch_bounds__(256, 4) void k2_mamba(
    unsigned char* __restrict__ ws,
    const float* __restrict__ cwf, const float* __restrict__ cbf,
    const float* __restrict__ dtbf, const float* __restrict__ alf,
    const float* __restrict__ Dpf,
    const float* __restrict__ cwb, const float* __restrict__ cbb,
    const float* __restrict__ dtbb, const float* __restrict__ alb,
    const float* __restrict__ Dpb)
{
  __shared__ unsigned short uld[2][30][272];   // 32640 B
  int blk = blockIdx.x;                        // 4096 = 2(b) x 2(tb) x 1024(pb-pairs)
  int b = blk >> 11; int tb = (blk >> 10) & 1; int pbh = blk & 1023;
  int wid = threadIdx.x >> 6, lane = threadIdx.x & 63;
  int pairIdx = wid >> 1, dir = wid & 1;
  int pb = pbh * 2 + pairIdx;

  // --- phase 1: u = xn @ W_in via MFMA; wave-half 'dir' computes rows dir*16.. ---
  const unsigned short* xn = (const unsigned short*)(ws + WS_XN);
  int lr = dir * 16 + (lane & 15); if (lr > 29) lr = 29;
  int g0r = lr / 10, g1r = lr - g0r * 10;
  const unsigned short* arow = xn + (((size_t)(b * TT + tb * 3 + g0r) * PP) + (size_t)pb * 10 + g1r) * 128 + (lane >> 4) * 8;
  short8 afr[4];
  #pragma unroll
  for (int kk = 0; kk < 4; kk++) afr[kk] = *(const short8*)(arow + kk * 32);
  const short8* bbm = (const short8*)(ws + WS_WIN);
  int row0 = dir * 16 + (lane >> 4) * 4;
  int col0 = lane & 15;
  #pragma unroll
  for (int half = 0; half < 2; half++){
    const int n0 = half ? 9 : 0;
    const int cnt = half ? 8 : 9;
    f32x4 acc[9];
    #pragma unroll
    for (int i = 0; i < 9; i++) acc[i] = (f32x4){0.f,0.f,0.f,0.f};
    #pragma unroll
    for (int kk = 0; kk < 4; kk++){
      #pragma unroll
      for (int j = 0; j < 9; j++){
        if (j < cnt){
          short8 bf = bbm[((n0 + j) * 4 + kk) * 64 + lane];
          acc[j] = __builtin_amdgcn_mfma_f32_16x16x32_bf16(afr[kk], bf, acc[j], 0, 0, 0);
        }
      }
    }
    #pragma unroll
    for (int j = 0; j < 9; j++){
      if (j < cnt){
        int col = (n0 + j) * 16 + col0;
        #pragma unroll
        for (int r2 = 0; r2 < 4; r2++){
          int row = row0 + r2;
          if (row < 30 && col < 266) uld[pairIdx][row][col] = f2bf(acc[j][r2]);
        }
      }
    }
  }
  __syncthreads();

  // --- phase 2: scan. dir=0 fwd, dir=1 bwd ---
  const float* cw  = dir ? cwb  : cwf;
  const float* cb  = dir ? cbb  : cbf;
  const float* dtb = dir ? dtbb : dtbf;
  const float* al  = dir ? alb  : alf;
  const float* Dp  = dir ? Dpb  : Dpf;
  unsigned int* ybuf = (unsigned int*)(ws + (dir ? WS_YB : WS_YF));
  int pbown = dir ? (2047 - pb) : pb;
  int cbase = (tb * 1024 + (pbown >> 1)) * 6 + (pbown & 1);
  unsigned int wbase = (unsigned int)b * 7864320u + (unsigned int)lane;

  int c0 = lane * 2;
  int hh = lane >> 3;
  float w00=cw[c0*3+0], w01=cw[c0*3+1], w02=cw[c0*3+2], cb0=cb[c0];
  float w10=cw[c0*3+3], w11=cw[c0*3+4], w12=cw[c0*3+5], cb1=cb[c0+1];
  float wB0=cw[128*3+0], wB1=cw[128*3+1], wB2=cw[128*3+2], cbB=cb[128];
  float wC0=cw[129*3+0], wC1=cw[129*3+1], wC2=cw[129*3+2], cbC=cb[129];
  float Ah = -__expf(al[hh]);
  float dtbh = dtb[hh], Dh = Dp[hh];
  const unsigned short* tile = &uld[pairIdx][0][0];

  float xp10=0,xp20=0,xp11=0,xp21=0, Bp1=0,Bp2=0, Cp1=0,Cp2=0;
  float h0=0.f, h1=0.f;
  #pragma unroll
  for (int l = 0; l < 30; l++){
    const int Kl = (l/3)*12288 + (l%3)*2;      // compile-time
    const int Kd = Kl / 20480, Km = Kl % 20480;
    const int urow_b = (l/10)*10 + 9 - (l%10); // compile-time
    const unsigned short* ur = tile + (dir ? urow_b : l) * 272;
    unsigned int zz = *(const unsigned int*)(ur + c0);
    unsigned int xx = *(const unsigned int*)(ur + 128 + c0);
    unsigned int bcw = *(const unsigned int*)(ur + 256);
    float dtr = asf((unsigned int)ur[258 + hh] << 16);
    float z0 = asf(zz << 16), z1 = asf(zz & 0xffff0000u);
    float xr0 = asf(xx << 16), xr1 = asf(xx & 0xffff0000u);
    float Br = asf(bcw << 16), Cr = asf(bcw & 0xffff0000u);
    float xc0 = fmaf(w02, xr0, fmaf(w01, xp10, fmaf(w00, xp20, cb0)));
    float xc1 = fmaf(w12, xr1, fmaf(w11, xp11, fmaf(w10, xp21, cb1)));
    float Bc  = fmaf(wB2, Br, fmaf(wB1, Bp1, fmaf(wB0, Bp2, cbB)));
    float Cc  = fmaf(wC2, Cr, fmaf(wC1, Cp1, fmaf(wC0, Cp2, cbC)));
    xp20=xp10; xp10=xr0; xp21=xp11; xp11=xr1;
    Bp2=Bp1; Bp1=Br; Cp2=Cp1; Cp1=Cr;
    float xh0 = xc0 * fast_sigm(xc0), xh1 = xc1 * fast_sigm(xc1);
    float Bv = Bc * fast_sigm(Bc), Cv = Cc * fast_sigm(Cc);
    float dtx = dtr + dtbh;
    float e = __expf(-fabsf(dtx));
    float dt = fmaxf(dtx, 0.0f) + __logf(1.0f + e);     // softplus
    float dA = __expf(dt * Ah);
    float sB = dt * Bv;
    h0 = fmaf(h0, dA, xh0 * sB);
    h1 = fmaf(h1, dA, xh1 * sB);
    float y0 = fmaf(h0, Cv, xh0 * Dh) * (z0 * fast_sigm(z0));
    float y1 = fmaf(h1, Cv, xh1 * Dh) * (z1 * fast_sigm(z1));
    unsigned int pk;
    asm("v_cvt_pk_bf16_f32 %0, %1, %2" : "=v"(pk) : "v"(y0), "v"(y1));
    int pD = Km + cbase, tD = Kd;
    if (pD >= 20480){ pD -= 20480; tD++; }
    if (dir) pD = 20479 - pD;
    ybuf[wbase + (unsigned int)tD * 1310720u + (unsigned int)pD * 64u] = pk;
  }
}

// ---------------- K3: fused epilogue (now also applies both RMSNorms) ----------------
__global__ __launch_bounds__(256) void k3_epi(
    const unsigned char* __restrict__ ws,
    const float* __restrict__ x, const float* __restrict__ xst,
    const int* __restrict__ curves,
    const float* __restrict__ nwf, const float* __restrict__ nwb,
    const float* __restrict__ l2w, const float* __restrict__ l2b,
    const float* __restrict__ b1, const float* __restrict__ b2,
    float* __restrict__ out)
{
  __shared__ unsigned short Abuf[64 * 128];   // swizzled bf16 A-tile (reused 3x)
  __shared__ float X1[64][101];               // x1 fp32 (conflict-reduced stride)
  int tid = threadIdx.x; int lane = tid & 63; int w = tid >> 6;
  size_t pos0 = (size_t)blockIdx.x * 64;
  int b = (int)(pos0 / (TT * PP)); int rm = (int)(pos0 % (TT * PP));
  int t = rm / PP; int p0 = rm % PP;

  // stage 0: rms-normalize yf,yb rows; A1 = bf16(0.5*(yf_n*nwf + yb_n*nwb)), swizzled
  {
    float nf0 = nwf[2*lane], nf1 = nwf[2*lane+1];
    float nb0 = nwb[2*lane], nb1 = nwb[2*lane+1];
    const unsigned int* yf = (const unsigned int*)(ws + WS_YF) + pos0 * 64;
    const unsigned int* yb = (const unsigned int*)(ws + WS_YB) + pos0 * 64;
    #pragma unroll 4
    for (int k = 0; k < 16; k++){
      int pr = k * 4 + w;
      unsigned int a = yf[pr * 64 + lane], c = yb[pr * 64 + lane];
      float f0 = asf(a << 16), f1 = asf(a & 0xffff0000u);
      float g0 = asf(c << 16), g1 = asf(c & 0xffff0000u);
      float sf = f0*f0 + f1*f1, sb = g0*g0 + g1*g1;
      #pragma unroll
      for (int m = 1; m < 64; m <<= 1){ sf += __shfl_xor(sf, m); sb += __shfl_xor(sb, m); }
      float rf = __builtin_amdgcn_rsqf(sf * (1.0f/128.0f) + EPSc);
      float rb = __builtin_amdgcn_rsqf(sb * (1.0f/128.0f) + EPSc);
      float lo = 0.5f * (f0 * rf * nf0 + g0 * rb * nb0);
      float hi = 0.5f * (f1 * rf * nf1 + g1 * rb * nb1);
      unsigned int pk;
      asm("v_cvt_pk_bf16_f32 %0, %1, %2" : "=v"(pk) : "v"(lo), "v"(hi));
      int off = pr * 256 + ((lane * 4) ^ ((pr & 7) << 5));
      *(unsigned int*)((unsigned char*)Abuf + off) = pk;
    }
  }
  __syncthreads();

  // stage 1: x1 = y @ W_out + xg
  f32x4 acc[6];
  #pragma unroll
  for (int i = 0; i < 6; i++) acc[i] = (f32x4){0.f,0.f,0.f,0.f};
  {
    int arow = w * 16 + (lane & 15);
    const short8* bbm = (const short8*)(ws + WS_WOUT);
    #pragma unroll
    for (int kk = 0; kk < 4; kk++){
      int off = arow * 256 + ((kk * 64 + (lane >> 4) * 16) ^ ((arow & 7) << 5));
      short8 af = *(const short8*)((const unsigned char*)Abuf + off);
      #pragma unroll
      for (int nt = 0; nt < 6; nt++){
        short8 bf = bbm[(nt * 4 + kk) * 64 + lane];
        acc[nt] = __builtin_amdgcn_mfma_f32_16x16x32_bf16(af, bf, acc[nt], 0, 0, 0);
      }
    }
    int row0 = w * 16 + (lane >> 4) * 4;
    int col = lane & 15;
    const int* cur = curves + b * PP;
    #pragma unroll
    for (int r2 = 0; r2 < 4; r2++){
      int row = row0 + r2;
      int cp = cur[p0 + row];
      const float* xr = x + ((size_t)(b * TT + t) * PP + cp) * 96;
      #pragma unroll
      for (int nt = 0; nt < 6; nt++){
        int n = nt * 16 + col;
        X1[row][n] = acc[nt][r2] + xr[n];
      }
    }
  }
  __syncthreads();

  // stage 2: t1 = LN(x1) + tanh(xs @ loan2 + l2b) -> A2 (bf16 swizzled)
  {
    int pr = tid >> 2, qq = tid & 3;
    float s = 0.f, ssq = 0.f;
    #pragma unroll
    for (int j = 0; j < 24; j++){ float v = X1[pr][qq * 24 + j]; s += v; ssq += v * v; }
    s += __shfl_xor(s, 1); ssq += __shfl_xor(ssq, 1);
    s += __shfl_xor(s, 2); ssq += __shfl_xor(ssq, 2);
    float mu = s * (1.0f / 96.0f);
    float rsv = __builtin_amdgcn_rsqf(ssq * (1.0f / 96.0f) - mu * mu + EPSc);
    int cp = curves[b * PP + p0 + pr];
    const float* xsr = xst + ((size_t)(b * TT + t) * PP + cp) * 8;
    float xsv[8];
    #pragma unroll
    for (int d = 0; d < 8; d++) xsv[d] = xsr[d];
    for (int j = 0; j < 24; j++){
      int cch = qq * 24 + j;
      float a = l2b[cch];
      #pragma unroll
      for (int d = 0; d < 8; d++) a += xsv[d] * l2w[d * 96 + cch];
      float t1 = (X1[pr][cch] - mu) * rsv + fast_tanh(a);
      int off = pr * 256 + ((cch * 2) ^ ((pr & 7) << 5));
      *(unsigned short*)((unsigned char*)Abuf + off) = f2bf(t1);
    }
  }
  __syncthreads();

  // stage 3: m = gelu(t1 @ W1 + b1) -> A3
  f32x4 acc2[6];
  #pragma unroll
  for (int i = 0; i < 6; i++) acc2[i] = (f32x4){0.f,0.f,0.f,0.f};
  {
    int arow = w * 16 + (lane & 15);
    const short8* bbm = (const short8*)(ws + WS_W1);
    #pragma unroll
    for (int kk = 0; kk < 3; kk++){
      int off = arow * 256 + ((kk * 64 + (lane >> 4) * 16) ^ ((arow & 7) << 5));
      short8 af = *(const short8*)((const unsigned char*)Abuf + off);
      #pragma unroll
      for (int nt = 0; nt < 6; nt++){
        short8 bf = bbm[(nt * 3 + kk) * 64 + lane];
        acc2[nt] = __builtin_amdgcn_mfma_f32_16x16x32_bf16(af, bf, acc2[nt], 0, 0, 0);
      }
    }
  }
  __syncthreads();
  {
    int row0 = w * 16 + (lane >> 4) * 4;
    int col = lane & 15;
    #pragma unroll
    for (int nt = 0; nt < 6; nt++){
      int n = nt * 16 + col;
      float bv = b1[n];
      #pragma unroll
      for (int r2 = 0; r2 < 4; r2++){
        float g = fast_gelu(acc2[nt][r2] + bv);
        int row = row0 + r2;
        int off = row * 256 + ((n * 2) ^ ((row & 7) << 5));
        *(unsigned short*)((unsigned char*)Abuf + off) = f2bf(g);
      }
    }
  }
  __syncthreads();

  // stage 4: out = gelu @ W2 + b2 + x1
  f32x4 acc3[6];
  #pragma unroll
  for (int i = 0; i < 6; i++) acc3[i] = (f32x4){0.f,0.f,0.f,0.f};
  {
    int arow = w * 16 + (lane & 15);
    const short8* bbm = (const short8*)(ws + WS_W2);
    #pragma unroll
    for (int kk = 0; kk < 3; kk++){
      int off = arow * 256 + ((kk * 64 + (lane >> 4) * 16) ^ ((arow & 7) << 5));
      short8 af = *(const short8*)((const unsigned char*)Abuf + off);
      #pragma unroll
      for (int nt = 0; nt < 6; nt++){
        short8 bf = bbm[(nt * 3 + kk) * 64 + lane];
        acc3[nt] = __builtin_amdgcn_mfma_f32_16x16x32_bf16(af, bf, acc3[nt], 0, 0, 0);
      }
    }
    int row0 = w * 16 + (lane >> 4) * 4;
    int col = lane & 15;
    #pragma unroll
    for (int r2 = 0; r2 < 4; r2++){
      int row = row0 + r2;
      size_t obase = ((size_t)(b * TT + t) * PP + (p0 + row)) * 96;
      #pragma unroll
      for (int nt = 0; nt < 6; nt++){
        int n = nt * 16 + col;
        out[obase + n] = acc3[nt][r2] + b2[n] + X1[row][n];
      }
    }
  }
}

extern "C" void kernel_launch(void* const* d_in, const int* in_sizes, int n_in,
                              void* d_out, int out_size, void* d_ws, size_t ws_size,
                              hipStream_t stream)
{
  const float* x     = (const float*)d_in[0];
  const float* xst   = (const float*)d_in[1];
  const float* xhr   = (const float*)d_in[2];
  const int*   curves= (const int*)d_in[3];
  const float* embw  = (const float*)d_in[4];
  const float* embb  = (const float*)d_in[5];
  const float* l1w   = (const float*)d_in[6];
  const float* l1b   = (const float*)d_in[7];
  const float* l2w   = (const float*)d_in[8];
  const float* l2b   = (const float*)d_in[9];
  const float* winp  = (const float*)d_in[10];
  const float* cwf   = (const float*)d_in[11];
  const float* cbf   = (const float*)d_in[12];
  const float* dtbf  = (const float*)d_in[13];
  const float* alf   = (const float*)d_in[14];
  const float* Df    = (const float*)d_in[15];
  const float* nwf   = (const float*)d_in[16];
  const float* cwb   = (const float*)d_in[17];
  const float* cbb   = (const float*)d_in[18];
  const float* dtbb  = (const float*)d_in[19];
  const float* alb   = (const float*)d_in[20];
  const float* Db    = (const float*)d_in[21];
  const float* nwb   = (const float*)d_in[22];
  const float* wout  = (const float*)d_in[23];
  const float* w1    = (const float*)d_in[24];
  const float* b1    = (const float*)d_in[25];
  const float* w2    = (const float*)d_in[26];
  const float* b2    = (const float*)d_in[27];
  unsigned char* ws  = (unsigned char*)d_ws;

  k0_wprep<<<32, 256, 0, stream>>>(winp, wout, w1, w2, ws);
  k1_prep<<<61440, 256, 0, stream>>>(x, xst, xhr, curves, embw, embb, l1w, l1b, ws);
  k2_mamba<<<4096, 256, 0, stream>>>(ws, cwf, cbf, dtbf, alf, Df,
                                         cwb, cbb, dtbb, alb, Db);
  k3_epi<<<3840, 256, 0, stream>>>(ws, x, xst, curves, nwf, nwb, l2w, l2b, b1, b2, (float*)d_out);
}

// Round 4
// 602.645 us; speedup vs baseline: 1.4870x; 1.0495x over previous
//
#include <hip/hip_runtime.h>
#include <math.h>

typedef __attribute__((ext_vector_type(8))) short short8;
typedef __attribute__((ext_vector_type(4))) float f32x4;
typedef __attribute__((ext_vector_type(4))) unsigned int u32x4;

#define BB 2
#define TT 6
#define PP 20480
#define DIMX 96
#define DSTAT 8
#define INH 28
#define EMBH 32
#define DIN 128
#define CONVD 130
#define DPROJ 266
#define EPSc 1e-5f

// ws layout (bytes), all 16B aligned
#define WS_WIN   0u           // in_proj frags  [17][4][64] short8 = 69632
#define WS_WOUT  69632u       // out_proj frags [6][4][64]  short8 = 24576
#define WS_W1    94208u       // mlp_w1 frags   [6][3][64]  short8 = 18432
#define WS_W2    112640u      // mlp_w2 frags   [6][3][64]  short8 = 18432
#define WS_XN    131072u      // xn bf16 [245760][128] = 62914560
#define WS_YF    63045632u    // y_f bf16 (pre-norm) [B][T][P][128] = 62914560
#define WS_YB    125960192u   // y_b bf16 (pre-norm, pre-flipped dest) = 62914560

__device__ __forceinline__ float asf(unsigned int u){ float f; __builtin_memcpy(&f, &u, 4); return f; }
__device__ __forceinline__ unsigned short f2bf(float f){
  unsigned int u; __builtin_memcpy(&u, &f, 4);
  unsigned int r = (u + 0x7fffu + ((u >> 16) & 1u)) >> 16;
  return (unsigned short)r;
}
__device__ __forceinline__ float fast_sigm(float x){ return __builtin_amdgcn_rcpf(1.0f + __expf(-x)); }
__device__ __forceinline__ float fast_tanh(float x){ return 1.0f - 2.0f * __builtin_amdgcn_rcpf(1.0f + __expf(2.0f * x)); }
__device__ __forceinline__ float fast_gelu(float v){
  float s = v * 0.70710678118654752f;
  float ax = fabsf(s);
  float t = __builtin_amdgcn_rcpf(1.0f + 0.3275911f * ax);
  float p = t * (0.254829592f + t * (-0.284496736f + t * (1.421413741f + t * (-1.453152027f + t * 1.061405429f))));
  float er = 1.0f - p * __expf(-ax * ax);
  er = (s < 0.0f) ? -er : er;
  return 0.5f * v * (1.0f + er);
}

// ---------------- K0: weight prep -> bf16 MFMA B-fragments ----------------
__global__ __launch_bounds__(256) void k0_wprep(
    const float* __restrict__ win, const float* __restrict__ wout,
    const float* __restrict__ w1, const float* __restrict__ w2,
    unsigned char* __restrict__ ws)
{
  int gt = blockIdx.x * 256 + threadIdx.x;
  int g = gt >> 6, lane = gt & 63;
  const float* src; int N; int gl; unsigned int dst;
  if (g < 68)       { src = win;  N = 266; gl = g;       dst = WS_WIN;  }
  else if (g < 92)  { src = wout; N = 96;  gl = g - 68;  dst = WS_WOUT; }
  else if (g < 110) { src = w1;   N = 96;  gl = g - 92;  dst = WS_W1;   }
  else              { src = w2;   N = 96;  gl = g - 110; dst = WS_W2;   }
  int kk, nt;
  if (g < 92) { nt = gl / 4; kk = gl % 4; } else { nt = gl / 3; kk = gl % 3; }
  int n = nt * 16 + (lane & 15);
  int k0 = kk * 32 + (lane >> 4) * 8;
  union { unsigned short u[8]; short8 s; } cv;
  #pragma unroll
  for (int j = 0; j < 8; j++){
    float f = (n < N) ? src[(size_t)(k0 + j) * N + n] : 0.0f;
    cv.u[j] = f2bf(f);
  }
  *(short8*)(ws + dst + (size_t)(gl * 64 + lane) * 16) = cv.s;
}

// ---------------- K1: gather + embed(MFMA) + LN + loan1 -> xn (bf16) ----------------
// 256 threads = 64 positions. Phase A: wave w does embed MFMA for positions w*16..+15.
// Phase B: 4 threads per position, 32 contiguous channels each (q=3 -> hr from LDS).
__global__ __launch_bounds__(256) void k1_prep(
    const float* __restrict__ x, const float* __restrict__ xst,
    const float* __restrict__ xhr, const int* __restrict__ curves,
    const float* __restrict__ ew, const float* __restrict__ eb,
    const float* __restrict__ l1w, const float* __restrict__ l1b,
    unsigned char* __restrict__ ws)
{
  __shared__ float hr[64][36];   // padded: row stride 144B (16B aligned, bank-shift 4)
  int tid = threadIdx.x, lane = tid & 63, w = tid >> 6;
  int pos0 = blockIdx.x * 64;    // 64 positions, all same (b,t) since P%64==0
  int b = pos0 / (TT * PP); int r = pos0 % (TT * PP);
  int t = r / PP; int p0 = r % PP;
  size_t tbase = (size_t)(b * TT + t) * PP;
  const int* cur = curves + b * PP + p0;

  // ---- Phase-B prefetch (issue gathered x loads early, consume after barrier) ----
  int pp = tid >> 2, q = tid & 3;
  int cpB = cur[pp];
  union { float4 v4[8]; float v[32]; } xv;
  if (q < 3){
    const float* xrowB = x + (tbase + cpB) * 96 + q * 32;
    #pragma unroll
    for (int j = 0; j < 8; j++) xv.v4[j] = *(const float4*)(xrowB + j * 4);
  }
  float xs[8];
  {
    const float4* xsr = (const float4*)(xst + (tbase + cpB) * 8);
    float4 a = xsr[0], bq = xsr[1];
    xs[0]=a.x; xs[1]=a.y; xs[2]=a.z; xs[3]=a.w;
    xs[4]=bq.x; xs[5]=bq.y; xs[6]=bq.z; xs[7]=bq.w;
  }

  // ---- Phase A: hr = tanh(xhr @ ew + eb) via MFMA, 16 positions per wave ----
  {
    int arow = w * 16 + (lane & 15);
    int g = lane >> 4;
    int cpA = cur[arow];
    const float* hrow = xhr + (tbase + cpA) * 28;
    float4 f0 = *(const float4*)(hrow + g * 8);
    float4 f1 = (g < 3) ? *(const float4*)(hrow + g * 8 + 4) : (float4){0.f,0.f,0.f,0.f};
    union { unsigned short u[8]; short8 s; } a8;
    a8.u[0]=f2bf(f0.x); a8.u[1]=f2bf(f0.y); a8.u[2]=f2bf(f0.z); a8.u[3]=f2bf(f0.w);
    a8.u[4]=f2bf(f1.x); a8.u[5]=f2bf(f1.y); a8.u[6]=f2bf(f1.z); a8.u[7]=f2bf(f1.w);
    union { unsigned short u[8]; short8 s; } b0, b1;
    #pragma unroll
    for (int j = 0; j < 8; j++){
      int k = g * 8 + j;
      if (k < 28){
        b0.u[j] = f2bf(ew[k * 32 + (lane & 15)]);
        b1.u[j] = f2bf(ew[k * 32 + 16 + (lane & 15)]);
      } else { b0.u[j] = 0; b1.u[j] = 0; }
    }
    f32x4 ac0 = {0.f,0.f,0.f,0.f}, ac1 = {0.f,0.f,0.f,0.f};
    ac0 = __builtin_amdgcn_mfma_f32_16x16x32_bf16(a8.s, b0.s, ac0, 0, 0, 0);
    ac1 = __builtin_amdgcn_mfma_f32_16x16x32_bf16(a8.s, b1.s, ac1, 0, 0, 0);
    float e0 = eb[lane & 15], e1 = eb[16 + (lane & 15)];
    int row0 = w * 16 + g * 4;
    #pragma unroll
    for (int rr = 0; rr < 4; rr++){
      hr[row0 + rr][lane & 15]        = fast_tanh(ac0[rr] + e0);
      hr[row0 + rr][16 + (lane & 15)] = fast_tanh(ac1[rr] + e1);
    }
  }
  __syncthreads();

  if (q == 3){
    #pragma unroll
    for (int j = 0; j < 8; j++) xv.v4[j] = *(const float4*)(&hr[pp][j * 4]);
  }
  // ---- LN over 128 (4-thread reduce) ----
  float s = 0.f, s2 = 0.f;
  #pragma unroll
  for (int j = 0; j < 32; j++){ float v = xv.v[j]; s += v; s2 += v * v; }
  s += __shfl_xor(s, 1); s2 += __shfl_xor(s2, 1);
  s += __shfl_xor(s, 2); s2 += __shfl_xor(s2, 2);
  float mu = s * (1.0f / 128.0f);
  float rs = __builtin_amdgcn_rsqf(s2 * (1.0f / 128.0f) - mu * mu + EPSc);
  // ---- loan1 (vectorized) ----
  float acc[32];
  {
    const float4* lb4 = (const float4*)(l1b + q * 32);
    #pragma unroll
    for (int jj = 0; jj < 8; jj++){
      float4 bv = lb4[jj];
      acc[jj*4]=bv.x; acc[jj*4+1]=bv.y; acc[jj*4+2]=bv.z; acc[jj*4+3]=bv.w;
    }
    #pragma unroll
    for (int d = 0; d < 8; d++){
      const float4* lw4 = (const float4*)(l1w + d * 128 + q * 32);
      float xd = xs[d];
      #pragma unroll
      for (int jj = 0; jj < 8; jj++){
        float4 wv = lw4[jj];
        acc[jj*4]   = fmaf(xd, wv.x, acc[jj*4]);
        acc[jj*4+1] = fmaf(xd, wv.y, acc[jj*4+1]);
        acc[jj*4+2] = fmaf(xd, wv.z, acc[jj*4+2]);
        acc[jj*4+3] = fmaf(xd, wv.w, acc[jj*4+3]);
      }
    }
  }
  unsigned int pk[16];
  #pragma unroll
  for (int j = 0; j < 16; j++){
    float r0 = (xv.v[2*j]   - mu) * rs + fast_tanh(acc[2*j]);
    float r1 = (xv.v[2*j+1] - mu) * rs + fast_tanh(acc[2*j+1]);
    asm("v_cvt_pk_bf16_f32 %0, %1, %2" : "=v"(pk[j]) : "v"(r0), "v"(r1));
  }
  u32x4* dst = (u32x4*)((unsigned short*)(ws + WS_XN) + (size_t)(pos0 + pp) * 128 + q * 32);
  #pragma unroll
  for (int j2 = 0; j2 < 4; j2++){
    u32x4 stv = { pk[j2*4], pk[j2*4+1], pk[j2*4+2], pk[j2*4+3] };
    dst[j2] = stv;
  }
}

// ---------------- K2: fused in_proj MFMA + bidirectional Mamba scan ----------------
// 256 threads = 4 waves = 2 window-pairs. pair = wid>>1, dir = wid&1.
// Stores y PRE-RMSNorm (norm deferred to K3).
__global__ __launch_bounds__(256, 4) void k2_mamba(
    unsigned char* __restrict__ ws,
    const float* __restrict__ cwf, const float* __restrict__ cbf,
    const float* __restrict__ dtbf, const float* __restrict__ alf,
    const float* __restrict__ Dpf,
    const float* __restrict__ cwb, const float* __restrict__ cbb,
    const float* __restrict__ dtbb, const float* __restrict__ alb,
    const float* __restrict__ Dpb)
{
  __shared__ unsigned short uld[2][30][272];   // 32640 B
  int blk = blockIdx.x;                        // 4096 = 2(b) x 2(tb) x 1024(pb-pairs)
  int b = blk >> 11; int tb = (blk >> 10) & 1; int pbh = blk & 1023;
  int wid = threadIdx.x >> 6, lane = threadIdx.x & 63;
  int pairIdx = wid >> 1, dir = wid & 1;
  int pb = pbh * 2 + pairIdx;

  // --- phase 1: u = xn @ W_in via MFMA; wave-half 'dir' computes rows dir*16.. ---
  const unsigned short* xn = (const unsigned short*)(ws + WS_XN);
  int lr = dir * 16 + (lane & 15); if (lr > 29) lr = 29;
  int g0r = lr / 10, g1r = lr - g0r * 10;
  const unsigned short* arow = xn + (((size_t)(b * TT + tb * 3 + g0r) * PP) + (size_t)pb * 10 + g1r) * 128 + (lane >> 4) * 8;
  short8 afr[4];
  #pragma unroll
  for (int kk = 0; kk < 4; kk++) afr[kk] = *(const short8*)(arow + kk * 32);
  const short8* bbm = (const short8*)(ws + WS_WIN);
  int row0 = dir * 16 + (lane >> 4) * 4;
  int col0 = lane & 15;
  #pragma unroll
  for (int half = 0; half < 2; half++){
    const int n0 = half ? 9 : 0;
    const int cnt = half ? 8 : 9;
    f32x4 acc[9];
    #pragma unroll
    for (int i = 0; i < 9; i++) acc[i] = (f32x4){0.f,0.f,0.f,0.f};
    #pragma unroll
    for (int kk = 0; kk < 4; kk++){
      #pragma unroll
      for (int j = 0; j < 9; j++){
        if (j < cnt){
          short8 bf = bbm[((n0 + j) * 4 + kk) * 64 + lane];
          acc[j] = __builtin_amdgcn_mfma_f32_16x16x32_bf16(afr[kk], bf, acc[j], 0, 0, 0);
        }
      }
    }
    #pragma unroll
    for (int j = 0; j < 9; j++){
      if (j < cnt){
        int col = (n0 + j) * 16 + col0;
        #pragma unroll
        for (int r2 = 0; r2 < 4; r2++){
          int row = row0 + r2;
          if (row < 30 && col < 266) uld[pairIdx][row][col] = f2bf(acc[j][r2]);
        }
      }
    }
  }
  __syncthreads();

  // --- phase 2: scan. dir=0 fwd, dir=1 bwd ---
  const float* cw  = dir ? cwb  : cwf;
  const float* cb  = dir ? cbb  : cbf;
  const float* dtb = dir ? dtbb : dtbf;
  const float* al  = dir ? alb  : alf;
  const float* Dp  = dir ? Dpb  : Dpf;
  unsigned int* ybuf = (unsigned int*)(ws + (dir ? WS_YB : WS_YF));
  int pbown = dir ? (2047 - pb) : pb;
  int cbase = (tb * 1024 + (pbown >> 1)) * 6 + (pbown & 1);
  unsigned int wbase = (unsigned int)b * 7864320u + (unsigned int)lane;

  int c0 = lane * 2;
  int hh = lane >> 3;
  float w00=cw[c0*3+0], w01=cw[c0*3+1], w02=cw[c0*3+2], cb0=cb[c0];
  float w10=cw[c0*3+3], w11=cw[c0*3+4], w12=cw[c0*3+5], cb1=cb[c0+1];
  float wB0=cw[128*3+0], wB1=cw[128*3+1], wB2=cw[128*3+2], cbB=cb[128];
  float wC0=cw[129*3+0], wC1=cw[129*3+1], wC2=cw[129*3+2], cbC=cb[129];
  float Ah = -__expf(al[hh]);
  float dtbh = dtb[hh], Dh = Dp[hh];
  const unsigned short* tile = &uld[pairIdx][0][0];

  float xp10=0,xp20=0,xp11=0,xp21=0, Bp1=0,Bp2=0, Cp1=0,Cp2=0;
  float h0=0.f, h1=0.f;
  #pragma unroll
  for (int l = 0; l < 30; l++){
    const int Kl = (l/3)*12288 + (l%3)*2;      // compile-time
    const int Kd = Kl / 20480, Km = Kl % 20480;
    const int urow_b = (l/10)*10 + 9 - (l%10); // compile-time
    const unsigned short* ur = tile + (dir ? urow_b : l) * 272;
    unsigned int zz = *(const unsigned int*)(ur + c0);
    unsigned int xx = *(const unsigned int*)(ur + 128 + c0);
    unsigned int bcw = *(const unsigned int*)(ur + 256);
    float dtr = asf((unsigned int)ur[258 + hh] << 16);
    float z0 = asf(zz << 16), z1 = asf(zz & 0xffff0000u);
    float xr0 = asf(xx << 16), xr1 = asf(xx & 0xffff0000u);
    float Br = asf(bcw << 16), Cr = asf(bcw & 0xffff0000u);
    float xc0 = fmaf(w02, xr0, fmaf(w01, xp10, fmaf(w00, xp20, cb0)));
    float xc1 = fmaf(w12, xr1, fmaf(w11, xp11, fmaf(w10, xp21, cb1)));
    float Bc  = fmaf(wB2, Br, fmaf(wB1, Bp1, fmaf(wB0, Bp2, cbB)));
    float Cc  = fmaf(wC2, Cr, fmaf(wC1, Cp1, fmaf(wC0, Cp2, cbC)));
    xp20=xp10; xp10=xr0; xp21=xp11; xp11=xr1;
    Bp2=Bp1; Bp1=Br; Cp2=Cp1; Cp1=Cr;
    float xh0 = xc0 * fast_sigm(xc0), xh1 = xc1 * fast_sigm(xc1);
    float Bv = Bc * fast_sigm(Bc), Cv = Cc * fast_sigm(Cc);
    float dtx = dtr + dtbh;
    float e = __expf(-fabsf(dtx));
    float dt = fmaxf(dtx, 0.0f) + __logf(1.0f + e);     // softplus
    float dA = __expf(dt * Ah);
    float sB = dt * Bv;
    h0 = fmaf(h0, dA, xh0 * sB);
    h1 = fmaf(h1, dA, xh1 * sB);
    float y0 = fmaf(h0, Cv, xh0 * Dh) * (z0 * fast_sigm(z0));
    float y1 = fmaf(h1, Cv, xh1 * Dh) * (z1 * fast_sigm(z1));
    unsigned int pk;
    asm("v_cvt_pk_bf16_f32 %0, %1, %2" : "=v"(pk) : "v"(y0), "v"(y1));
    int pD = Km + cbase, tD = Kd;
    if (pD >= 20480){ pD -= 20480; tD++; }
    if (dir) pD = 20479 - pD;
    ybuf[wbase + (unsigned int)tD * 1310720u + (unsigned int)pD * 64u] = pk;
  }
}

// ---------------- K3: fused epilogue (now also applies both RMSNorms) ----------------
__global__ __launch_bounds__(256) void k3_epi(
    const unsigned char* __restrict__ ws,
    const float* __restrict__ x, const float* __restrict__ xst,
    const int* __restrict__ curves,
    const float* __restrict__ nwf, const float* __restrict__ nwb,
    const float* __restrict__ l2w, const float* __restrict__ l2b,
    const float* __restrict__ b1, const float* __restrict__ b2,
    float* __restrict__ out)
{
  __shared__ unsigned short Abuf[64 * 128];   // swizzled bf16 A-tile (reused 3x)
  __shared__ float X1[64][101];               // x1 fp32 (conflict-reduced stride)
  int tid = threadIdx.x; int lane = tid & 63; int w = tid >> 6;
  size_t pos0 = (size_t)blockIdx.x * 64;
  int b = (int)(pos0 / (TT * PP)); int rm = (int)(pos0 % (TT * PP));
  int t = rm / PP; int p0 = rm % PP;

  // stage 0: rms-normalize yf,yb rows; A1 = bf16(0.5*(yf_n*nwf + yb_n*nwb)), swizzled
  {
    float nf0 = nwf[2*lane], nf1 = nwf[2*lane+1];
    float nb0 = nwb[2*lane], nb1 = nwb[2*lane+1];
    const unsigned int* yf = (const unsigned int*)(ws + WS_YF) + pos0 * 64;
    const unsigned int* yb = (const unsigned int*)(ws + WS_YB) + pos0 * 64;
    #pragma unroll 4
    for (int k = 0; k < 16; k++){
      int pr = k * 4 + w;
      unsigned int a = yf[pr * 64 + lane], c = yb[pr * 64 + lane];
      float f0 = asf(a << 16), f1 = asf(a & 0xffff0000u);
      float g0 = asf(c << 16), g1 = asf(c & 0xffff0000u);
      float sf = f0*f0 + f1*f1, sb = g0*g0 + g1*g1;
      #pragma unroll
      for (int m = 1; m < 64; m <<= 1){ sf += __shfl_xor(sf, m); sb += __shfl_xor(sb, m); }
      float rf = __builtin_amdgcn_rsqf(sf * (1.0f/128.0f) + EPSc);
      float rb = __builtin_amdgcn_rsqf(sb * (1.0f/128.0f) + EPSc);
      float lo = 0.5f * (f0 * rf * nf0 + g0 * rb * nb0);
      float hi = 0.5f * (f1 * rf * nf1 + g1 * rb * nb1);
      unsigned int pk;
      asm("v_cvt_pk_bf16_f32 %0, %1, %2" : "=v"(pk) : "v"(lo), "v"(hi));
      int off = pr * 256 + ((lane * 4) ^ ((pr & 7) << 5));
      *(unsigned int*)((unsigned char*)Abuf + off) = pk;
    }
  }
  __syncthreads();

  // stage 1: x1 = y @ W_out + xg
  f32x4 acc[6];
  #pragma unroll
  for (int i = 0; i < 6; i++) acc[i] = (f32x4){0.f,0.f,0.f,0.f};
  {
    int arow = w * 16 + (lane & 15);
    const short8* bbm = (const short8*)(ws + WS_WOUT);
    #pragma unroll
    for (int kk = 0; kk < 4; kk++){
      int off = arow * 256 + ((kk * 64 + (lane >> 4) * 16) ^ ((arow & 7) << 5));
      short8 af = *(const short8*)((const unsigned char*)Abuf + off);
      #pragma unroll
      for (int nt = 0; nt < 6; nt++){
        short8 bf = bbm[(nt * 4 + kk) * 64 + lane];
        acc[nt] = __builtin_amdgcn_mfma_f32_16x16x32_bf16(af, bf, acc[nt], 0, 0, 0);
      }
    }
    int row0 = w * 16 + (lane >> 4) * 4;
    int col = lane & 15;
    const int* cur = curves + b * PP;
    #pragma unroll
    for (int r2 = 0; r2 < 4; r2++){
      int row = row0 + r2;
      int cp = cur[p0 + row];
      const float* xr = x + ((size_t)(b * TT + t) * PP + cp) * 96;
      #pragma unroll
      for (int nt = 0; nt < 6; nt++){
        int n = nt * 16 + col;
        X1[row][n] = acc[nt][r2] + xr[n];
      }
    }
  }
  __syncthreads();

  // stage 2: t1 = LN(x1) + tanh(xs @ loan2 + l2b) -> A2 (bf16 swizzled)
  {
    int pr = tid >> 2, qq = tid & 3;
    float s = 0.f, ssq = 0.f;
    #pragma unroll
    for (int j = 0; j < 24; j++){ float v = X1[pr][qq * 24 + j]; s += v; ssq += v * v; }
    s += __shfl_xor(s, 1); ssq += __shfl_xor(ssq, 1);
    s += __shfl_xor(s, 2); ssq += __shfl_xor(ssq, 2);
    float mu = s * (1.0f / 96.0f);
    float rsv = __builtin_amdgcn_rsqf(ssq * (1.0f / 96.0f) - mu * mu + EPSc);
    int cp = curves[b * PP + p0 + pr];
    const float* xsr = xst + ((size_t)(b * TT + t) * PP + cp) * 8;
    float xsv[8];
    #pragma unroll
    for (int d = 0; d < 8; d++) xsv[d] = xsr[d];
    for (int j = 0; j < 24; j++){
      int cch = qq * 24 + j;
      float a = l2b[cch];
      #pragma unroll
      for (int d = 0; d < 8; d++) a += xsv[d] * l2w[d * 96 + cch];
      float t1 = (X1[pr][cch] - mu) * rsv + fast_tanh(a);
      int off = pr * 256 + ((cch * 2) ^ ((pr & 7) << 5));
      *(unsigned short*)((unsigned char*)Abuf + off) = f2bf(t1);
    }
  }
  __syncthreads();

  // stage 3: m = gelu(t1 @ W1 + b1) -> A3
  f32x4 acc2[6];
  #pragma unroll
  for (int i = 0; i < 6; i++) acc2[i] = (f32x4){0.f,0.f,0.f,0.f};
  {
    int arow = w * 16 + (lane & 15);
    const short8* bbm = (const short8*)(ws + WS_W1);
    #pragma unroll
    for (int kk = 0; kk < 3; kk++){
      int off = arow * 256 + ((kk * 64 + (lane >> 4) * 16) ^ ((arow & 7) << 5));
      short8 af = *(const short8*)((const unsigned char*)Abuf + off);
      #pragma unroll
      for (int nt = 0; nt < 6; nt++){
        short8 bf = bbm[(nt * 3 + kk) * 64 + lane];
        acc2[nt] = __builtin_amdgcn_mfma_f32_16x16x32_bf16(af, bf, acc2[nt], 0, 0, 0);
      }
    }
  }
  __syncthreads();
  {
    int row0 = w * 16 + (lane >> 4) * 4;
    int col = lane & 15;
    #pragma unroll
    for (int nt = 0; nt < 6; nt++){
      int n = nt * 16 + col;
      float bv = b1[n];
      #pragma unroll
      for (int r2 = 0; r2 < 4; r2++){
        float g = fast_gelu(acc2[nt][r2] + bv);
        int row = row0 + r2;
        int off = row * 256 + ((n * 2) ^ ((row & 7) << 5));
        *(unsigned short*)((unsigned char*)Abuf + off) = f2bf(g);
      }
    }
  }
  __syncthreads();

  // stage 4: out = gelu @ W2 + b2 + x1
  f32x4 acc3[6];
  #pragma unroll
  for (int i = 0; i < 6; i++) acc3[i] = (f32x4){0.f,0.f,0.f,0.f};
  {
    int arow = w * 16 + (lane & 15);
    const short8* bbm = (const short8*)(ws + WS_W2);
    #pragma unroll
    for (int kk = 0; kk < 3; kk++){
      int off = arow * 256 + ((kk * 64 + (lane >> 4) * 16) ^ ((arow & 7) << 5));
      short8 af = *(const short8*)((const unsigned char*)Abuf + off);
      #pragma unroll
      for (int nt = 0; nt < 6; nt++){
        short8 bf = bbm[(nt * 3 + kk) * 64 + lane];
        acc3[nt] = __builtin_amdgcn_mfma_f32_16x16x32_bf16(af, bf, acc3[nt], 0, 0, 0);
      }
    }
    int row0 = w * 16 + (lane >> 4) * 4;
    int col = lane & 15;
    #pragma unroll
    for (int r2 = 0; r2 < 4; r2++){
      int row = row0 + r2;
      size_t obase = ((size_t)(b * TT + t) * PP + (p0 + row)) * 96;
      #pragma unroll
      for (int nt = 0; nt < 6; nt++){
        int n = nt * 16 + col;
        out[obase + n] = acc3[nt][r2] + b2[n] + X1[row][n];
      }
    }
  }
}

extern "C" void kernel_launch(void* const* d_in, const int* in_sizes, int n_in,
                              void* d_out, int out_size, void* d_ws, size_t ws_size,
                              hipStream_t stream)
{
  const float* x     = (const float*)d_in[0];
  const float* xst   = (const float*)d_in[1];
  const float* xhr   = (const float*)d_in[2];
  const int*   curves= (const int*)d_in[3];
  const float* embw  = (const float*)d_in[4];
  const float* embb  = (const float*)d_in[5];
  const float* l1w   = (const float*)d_in[6];
  const float* l1b   = (const float*)d_in[7];
  const float* l2w   = (const float*)d_in[8];
  const float* l2b   = (const float*)d_in[9];
  const float* winp  = (const float*)d_in[10];
  const float* cwf   = (const float*)d_in[11];
  const float* cbf   = (const float*)d_in[12];
  const float* dtbf  = (const float*)d_in[13];
  const float* alf   = (const float*)d_in[14];
  const float* Df    = (const float*)d_in[15];
  const float* nwf   = (const float*)d_in[16];
  const float* cwb   = (const float*)d_in[17];
  const float* cbb   = (const float*)d_in[18];
  const float* dtbb  = (const float*)d_in[19];
  const float* alb   = (const float*)d_in[20];
  const float* Db    = (const float*)d_in[21];
  const float* nwb   = (const float*)d_in[22];
  const float* wout  = (const float*)d_in[23];
  const float* w1    = (const float*)d_in[24];
  const float* b1    = (const float*)d_in[25];
  const float* w2    = (const float*)d_in[26];
  const float* b2    = (const float*)d_in[27];
  unsigned char* ws  = (unsigned char*)d_ws;

  k0_wprep<<<32, 256, 0, stream>>>(winp, wout, w1, w2, ws);
  k1_prep<<<3840, 256, 0, stream>>>(x, xst, xhr, curves, embw, embb, l1w, l1b, ws);
  k2_mamba<<<4096, 256, 0, stream>>>(ws, cwf, cbf, dtbf, alf, Df,
                                         cwb, cbb, dtbb, alb, Db);
  k3_epi<<<3840, 256, 0, stream>>>(ws, x, xst, curves, nwf, nwb, l2w, l2b, b1, b2, (float*)d_out);
}

// Round 6
// 455.391 us; speedup vs baseline: 1.9679x; 1.3234x over previous
//
#include <hip/hip_runtime.h>
#include <math.h>

typedef __attribute__((ext_vector_type(8))) short short8;
typedef __attribute__((ext_vector_type(4))) float f32x4;
typedef __attribute__((ext_vector_type(4))) unsigned int u32x4;

#define BB 2
#define TT 6
#define PP 20480
#define EPSc 1e-5f

// ws layout (bytes), all 16B aligned
#define WS_WIN   0u          // in_proj frags   [68][64] short8 = 69632
#define WS_WOF   69632u      // 0.5*nwf*Wout    [24][64] short8 = 24576
#define WS_WOB   94208u      // 0.5*nwb*Wout    [24][64] short8 = 24576
#define WS_W1    118784u     // mlp_w1 frags    [18][64] short8 = 18432
#define WS_W2    137216u     // mlp_w2 frags    [18][64] short8 = 18432
#define WS_EW    155648u     // embed frags(+eb row) [2][64] = 2048
#define WS_L1    157696u     // loan1 frags(+b row)  [8][64] = 8192
#define WS_L2    165888u     // loan2 frags(+b row)  [6][64] = 6144
#define WS_INV   172032u     // inverse perm int[2*20480] = 163840
#define WS_XN    335872u     // xn bf16 [245760][128] = 62914560
#define WS_YF    63250432u   // y_f bf16 (pre-norm) = 62914560
#define WS_YB    126164992u  // y_b bf16 (pre-norm, pre-flipped) = 62914560

__device__ __forceinline__ float asf(unsigned int u){ float f; __builtin_memcpy(&f, &u, 4); return f; }
__device__ __forceinline__ unsigned short f2bf(float f){
  unsigned int u; __builtin_memcpy(&u, &f, 4);
  unsigned int r = (u + 0x7fffu + ((u >> 16) & 1u)) >> 16;
  return (unsigned short)r;
}
__device__ __forceinline__ float fast_sigm(float x){ return __builtin_amdgcn_rcpf(1.0f + __expf(-x)); }
__device__ __forceinline__ float fast_tanh(float x){ return 1.0f - 2.0f * __builtin_amdgcn_rcpf(1.0f + __expf(2.0f * x)); }
__device__ __forceinline__ float fast_gelu(float v){
  float s = v * 0.70710678118654752f;
  float ax = fabsf(s);
  float t = __builtin_amdgcn_rcpf(1.0f + 0.3275911f * ax);
  float p = t * (0.254829592f + t * (-0.284496736f + t * (1.421413741f + t * (-1.453152027f + t * 1.061405429f))));
  float er = 1.0f - p * __expf(-ax * ax);
  er = (s < 0.0f) ? -er : er;
  return 0.5f * v * (1.0f + er);
}

// ---------------- K0: all weight prep -> bf16 MFMA B-fragments ----------------
// 168 groups of 64 lanes. frag(gl,lane,j) = W[k=kk*32+(lane>>4)*8+j][n=nt*16+(lane&15)]
__global__ __launch_bounds__(256) void k0_wprep(
    const float* __restrict__ win, const float* __restrict__ wout,
    const float* __restrict__ w1m, const float* __restrict__ w2m,
    const float* __restrict__ nwf, const float* __restrict__ nwb,
    const float* __restrict__ ew, const float* __restrict__ eb,
    const float* __restrict__ l1w, const float* __restrict__ l1b,
    const float* __restrict__ l2w, const float* __restrict__ l2b,
    unsigned char* __restrict__ ws)
{
  int gt = blockIdx.x * 256 + threadIdx.x;
  int g = gt >> 6, lane = gt & 63;
  int ln = lane & 15, kg = lane >> 4;
  union { unsigned short u[8]; short8 s; } cv;
  unsigned int dst; int gl;
  if (g < 68){
    gl = g; int nt = gl >> 2, kk = gl & 3;
    int n = nt * 16 + ln;
    #pragma unroll
    for (int j = 0; j < 8; j++){
      int k = kk * 32 + kg * 8 + j;
      cv.u[j] = f2bf((n < 266) ? win[(size_t)k * 266 + n] : 0.0f);
    }
    dst = WS_WIN;
  } else if (g < 116){
    int isb = (g >= 92); gl = g - (isb ? 92 : 68);
    int nt = gl >> 2, kk = gl & 3;
    int n = nt * 16 + ln;
    const float* nw = isb ? nwb : nwf;
    #pragma unroll
    for (int j = 0; j < 8; j++){
      int k = kk * 32 + kg * 8 + j;
      cv.u[j] = f2bf(0.5f * nw[k] * wout[(size_t)k * 96 + n]);
    }
    dst = isb ? WS_WOB : WS_WOF;
  } else if (g < 152){
    int is2 = (g >= 134); gl = g - (is2 ? 134 : 116);
    int nt = gl / 3, kk = gl % 3;
    int n = nt * 16 + ln;
    const float* src = is2 ? w2m : w1m;
    #pragma unroll
    for (int j = 0; j < 8; j++){
      int k = kk * 32 + kg * 8 + j;
      cv.u[j] = f2bf(src[(size_t)k * 96 + n]);
    }
    dst = is2 ? WS_W2 : WS_W1;
  } else if (g < 154){
    gl = g - 152; int n = gl * 16 + ln;
    #pragma unroll
    for (int j = 0; j < 8; j++){
      int k = kg * 8 + j;
      float f = (k < 28) ? ew[k * 32 + n] : ((k == 28) ? eb[n] : 0.0f);
      cv.u[j] = f2bf(f);
    }
    dst = WS_EW;
  } else if (g < 162){
    gl = g - 154; int n = gl * 16 + ln;
    #pragma unroll
    for (int j = 0; j < 8; j++){
      int k = kg * 8 + j;
      float f = (k < 8) ? l1w[k * 128 + n] : ((k == 8) ? l1b[n] : 0.0f);
      cv.u[j] = f2bf(f);
    }
    dst = WS_L1;
  } else {
    gl = g - 162; int n = gl * 16 + ln;
    #pragma unroll
    for (int j = 0; j < 8; j++){
      int k = kg * 8 + j;
      float f = (k < 8) ? l2w[k * 96 + n] : ((k == 8) ? l2b[n] : 0.0f);
      cv.u[j] = f2bf(f);
    }
    dst = WS_L2;
  }
  *(short8*)(ws + dst + (size_t)(gl * 64 + lane) * 16) = cv.s;
}

// ---------------- K0b: inverse permutation ----------------
__global__ __launch_bounds__(256) void k0b_inv(
    const int* __restrict__ curves, unsigned char* __restrict__ ws)
{
  int i = blockIdx.x * 256 + threadIdx.x;   // < 40960
  int p = i % PP;
  ((int*)(ws + WS_INV))[(i / PP) * PP + curves[i]] = p;
}

// ---------------- K1: SOURCE-ordered gather-free prep ----------------
// 256 threads = 64 source rows. Phase A: MFMA embed (+eb) and loan1 (+b) per wave.
// Phase B: 4 threads/row, coalesced x reads, LN, add tanh(loan1), scatter-store xn.
__global__ __launch_bounds__(256) void k1_prep(
    const float* __restrict__ x, const float* __restrict__ xst,
    const float* __restrict__ xhr, unsigned char* __restrict__ ws)
{
  __shared__ unsigned short hrl[4][16][40];    // tanh(embed), bf16
  __shared__ unsigned short lol[4][16][136];   // tanh(loan1), bf16
  int tid = threadIdx.x, lane = tid & 63, w = tid >> 6;
  int pos0 = blockIdx.x * 64;
  int b = pos0 / (TT * PP); int r = pos0 % (TT * PP);
  int t = r / PP; int c0 = r % PP;
  size_t tbase = (size_t)(b * TT + t) * PP;

  // ---- phase A ----
  {
    int arow = w * 16 + (lane & 15);
    int g = lane >> 4;
    const float* hrow = xhr + (tbase + c0 + arow) * 28;
    float4 f0 = *(const float4*)(hrow + g * 8);
    float4 f1 = (g < 3) ? *(const float4*)(hrow + g * 8 + 4) : (float4){0.f,0.f,0.f,0.f};
    const float4* xsr = (const float4*)(xst + (tbase + c0 + arow) * 8);
    float4 s0 = xsr[0], s1 = xsr[1];
    union { unsigned short u[8]; short8 s; } ae, al;
    ae.u[0]=f2bf(f0.x); ae.u[1]=f2bf(f0.y); ae.u[2]=f2bf(f0.z); ae.u[3]=f2bf(f0.w);
    ae.u[4]=f2bf(f1.x); ae.u[5]=f2bf(f1.y); ae.u[6]=f2bf(f1.z); ae.u[7]=f2bf(f1.w);
    if (g == 3){ ae.u[4] = 0x3F80u; ae.u[5]=0; ae.u[6]=0; ae.u[7]=0; }
    #pragma unroll
    for (int j = 0; j < 8; j++) al.u[j] = 0;
    if (g == 0){
      al.u[0]=f2bf(s0.x); al.u[1]=f2bf(s0.y); al.u[2]=f2bf(s0.z); al.u[3]=f2bf(s0.w);
      al.u[4]=f2bf(s1.x); al.u[5]=f2bf(s1.y); al.u[6]=f2bf(s1.z); al.u[7]=f2bf(s1.w);
    } else if (g == 1){ al.u[0] = 0x3F80u; }
    const short8* BE = (const short8*)(ws + WS_EW);
    const short8* BL = (const short8*)(ws + WS_L1);
    f32x4 he0 = {0.f,0.f,0.f,0.f}, he1 = {0.f,0.f,0.f,0.f};
    he0 = __builtin_amdgcn_mfma_f32_16x16x32_bf16(ae.s, BE[lane], he0, 0, 0, 0);
    he1 = __builtin_amdgcn_mfma_f32_16x16x32_bf16(ae.s, BE[64 + lane], he1, 0, 0, 0);
    f32x4 lo[8];
    #pragma unroll
    for (int nt = 0; nt < 8; nt++){
      f32x4 z = {0.f,0.f,0.f,0.f};
      lo[nt] = __builtin_amdgcn_mfma_f32_16x16x32_bf16(al.s, BL[nt * 64 + lane], z, 0, 0, 0);
    }
    int rl = (lane >> 4) * 4, col = lane & 15;
    #pragma unroll
    for (int r2 = 0; r2 < 4; r2++){
      hrl[w][rl + r2][col]      = f2bf(fast_tanh(he0[r2]));
      hrl[w][rl + r2][16 + col] = f2bf(fast_tanh(he1[r2]));
    }
    #pragma unroll
    for (int nt = 0; nt < 8; nt++){
      #pragma unroll
      for (int r2 = 0; r2 < 4; r2++)
        lol[w][rl + r2][nt * 16 + col] = f2bf(fast_tanh(lo[nt][r2]));
    }
  }
  __syncthreads();

  // ---- phase B ----
  int pp = tid >> 2, q = tid & 3;
  int c = c0 + pp;
  union { float4 v4[8]; float v[32]; } xv;
  if (q < 3){
    const float4* xr4 = (const float4*)(x + (tbase + c) * 96 + q * 32);
    #pragma unroll
    for (int j = 0; j < 8; j++) xv.v4[j] = xr4[j];
  } else {
    const u32x4* hp = (const u32x4*)(&hrl[pp >> 4][pp & 15][0]);
    #pragma unroll
    for (int j = 0; j < 4; j++){
      u32x4 hv = hp[j];
      #pragma unroll
      for (int e = 0; e < 4; e++){
        unsigned int u = hv[e];
        xv.v[j*8 + e*2]     = asf(u << 16);
        xv.v[j*8 + e*2 + 1] = asf(u & 0xffff0000u);
      }
    }
  }
  float s = 0.f, s2 = 0.f;
  #pragma unroll
  for (int j = 0; j < 32; j++){ float v = xv.v[j]; s += v; s2 += v * v; }
  s += __shfl_xor(s, 1); s2 += __shfl_xor(s2, 1);
  s += __shfl_xor(s, 2); s2 += __shfl_xor(s2, 2);
  float mu = s * (1.0f / 128.0f);
  float rs = __builtin_amdgcn_rsqf(s2 * (1.0f / 128.0f) - mu * mu + EPSc);

  int p = ((const int*)(ws + WS_INV))[b * PP + c];
  const u32x4* lp = (const u32x4*)(&lol[pp >> 4][pp & 15][q * 32]);
  u32x4* dst = (u32x4*)((unsigned short*)(ws + WS_XN) + (tbase + p) * 128 + q * 32);
  #pragma unroll
  for (int j = 0; j < 4; j++){
    u32x4 lv = lp[j];
    unsigned int pk[4];
    #pragma unroll
    for (int e = 0; e < 4; e++){
      unsigned int lu = lv[e];
      float l0 = asf(lu << 16), l1 = asf(lu & 0xffff0000u);
      int idx = j*8 + e*2;
      float r0 = (xv.v[idx]   - mu) * rs + l0;
      float r1 = (xv.v[idx+1] - mu) * rs + l1;
      asm("v_cvt_pk_bf16_f32 %0, %1, %2" : "=v"(pk[e]) : "v"(r0), "v"(r1));
    }
    u32x4 stv = { pk[0], pk[1], pk[2], pk[3] };
    dst[j] = stv;
  }
}

// ---------------- K2: fused in_proj MFMA + bidirectional Mamba scan ----------------
__global__ __launch_bounds__(256, 4) void k2_mamba(
    unsigned char* __restrict__ ws,
    const float* __restrict__ cwf, const float* __restrict__ cbf,
    const float* __restrict__ dtbf, const float* __restrict__ alf,
    const float* __restrict__ Dpf,
    const float* __restrict__ cwb, const float* __restrict__ cbb,
    const float* __restrict__ dtbb, const float* __restrict__ alb,
    const float* __restrict__ Dpb)
{
  __shared__ unsigned short uld[2][30][272];
  int blk = blockIdx.x;
  int b = blk >> 11; int tb = (blk >> 10) & 1; int pbh = blk & 1023;
  int wid = threadIdx.x >> 6, lane = threadIdx.x & 63;
  int pairIdx = wid >> 1, dir = wid & 1;
  int pb = pbh * 2 + pairIdx;

  const unsigned short* xn = (const unsigned short*)(ws + WS_XN);
  int lr = dir * 16 + (lane & 15); if (lr > 29) lr = 29;
  int g0r = lr / 10, g1r = lr - g0r * 10;
  const unsigned short* arow = xn + (((size_t)(b * TT + tb * 3 + g0r) * PP) + (size_t)pb * 10 + g1r) * 128 + (lane >> 4) * 8;
  short8 afr[4];
  #pragma unroll
  for (int kk = 0; kk < 4; kk++) afr[kk] = *(const short8*)(arow + kk * 32);
  const short8* bbm = (const short8*)(ws + WS_WIN);
  int row0 = dir * 16 + (lane >> 4) * 4;
  int col0 = lane & 15;
  #pragma unroll
  for (int half = 0; half < 2; half++){
    const int n0 = half ? 9 : 0;
    const int cnt = half ? 8 : 9;
    f32x4 acc[9];
    #pragma unroll
    for (int i = 0; i < 9; i++) acc[i] = (f32x4){0.f,0.f,0.f,0.f};
    #pragma unroll
    for (int kk = 0; kk < 4; kk++){
      #pragma unroll
      for (int j = 0; j < 9; j++){
        if (j < cnt){
          short8 bf = bbm[((n0 + j) * 4 + kk) * 64 + lane];
          acc[j] = __builtin_amdgcn_mfma_f32_16x16x32_bf16(afr[kk], bf, acc[j], 0, 0, 0);
        }
      }
    }
    #pragma unroll
    for (int j = 0; j < 9; j++){
      if (j < cnt){
        int col = (n0 + j) * 16 + col0;
        #pragma unroll
        for (int r2 = 0; r2 < 4; r2++){
          int row = row0 + r2;
          if (row < 30 && col < 266) uld[pairIdx][row][col] = f2bf(acc[j][r2]);
        }
      }
    }
  }
  __syncthreads();

  const float* cw  = dir ? cwb  : cwf;
  const float* cb  = dir ? cbb  : cbf;
  const float* dtb = dir ? dtbb : dtbf;
  const float* al  = dir ? alb  : alf;
  const float* Dp  = dir ? Dpb  : Dpf;
  unsigned int* ybuf = (unsigned int*)(ws + (dir ? WS_YB : WS_YF));
  int pbown = dir ? (2047 - pb) : pb;
  int cbase = (tb * 1024 + (pbown >> 1)) * 6 + (pbown & 1);
  unsigned int wbase = (unsigned int)b * 7864320u + (unsigned int)lane;

  int c0 = lane * 2;
  int hh = lane >> 3;
  float w00=cw[c0*3+0], w01=cw[c0*3+1], w02=cw[c0*3+2], cb0=cb[c0];
  float w10=cw[c0*3+3], w11=cw[c0*3+4], w12=cw[c0*3+5], cb1=cb[c0+1];
  float wB0=cw[128*3+0], wB1=cw[128*3+1], wB2=cw[128*3+2], cbB=cb[128];
  float wC0=cw[129*3+0], wC1=cw[129*3+1], wC2=cw[129*3+2], cbC=cb[129];
  float Ah = -__expf(al[hh]);
  float dtbh = dtb[hh], Dh = Dp[hh];
  const unsigned short* tile = &uld[pairIdx][0][0];

  float xp10=0,xp20=0,xp11=0,xp21=0, Bp1=0,Bp2=0, Cp1=0,Cp2=0;
  float h0=0.f, h1=0.f;
  #pragma unroll
  for (int l = 0; l < 30; l++){
    const int Kl = (l/3)*12288 + (l%3)*2;
    const int Kd = Kl / 20480, Km = Kl % 20480;
    const int urow_b = (l/10)*10 + 9 - (l%10);
    const unsigned short* ur = tile + (dir ? urow_b : l) * 272;
    unsigned int zz = *(const unsigned int*)(ur + c0);
    unsigned int xx = *(const unsigned int*)(ur + 128 + c0);
    unsigned int bcw = *(const unsigned int*)(ur + 256);
    float dtr = asf((unsigned int)ur[258 + hh] << 16);
    float z0 = asf(zz << 16), z1 = asf(zz & 0xffff0000u);
    float xr0 = asf(xx << 16), xr1 = asf(xx & 0xffff0000u);
    float Br = asf(bcw << 16), Cr = asf(bcw & 0xffff0000u);
    float xc0 = fmaf(w02, xr0, fmaf(w01, xp10, fmaf(w00, xp20, cb0)));
    float xc1 = fmaf(w12, xr1, fmaf(w11, xp11, fmaf(w10, xp21, cb1)));
    float Bc  = fmaf(wB2, Br, fmaf(wB1, Bp1, fmaf(wB0, Bp2, cbB)));
    float Cc  = fmaf(wC2, Cr, fmaf(wC1, Cp1, fmaf(wC0, Cp2, cbC)));
    xp20=xp10; xp10=xr0; xp21=xp11; xp11=xr1;
    Bp2=Bp1; Bp1=Br; Cp2=Cp1; Cp1=Cr;
    float xh0 = xc0 * fast_sigm(xc0), xh1 = xc1 * fast_sigm(xc1);
    float Bv = Bc * fast_sigm(Bc), Cv = Cc * fast_sigm(Cc);
    float dtx = dtr + dtbh;
    float e = __expf(-fabsf(dtx));
    float dt = fmaxf(dtx, 0.0f) + __logf(1.0f + e);
    float dA = __expf(dt * Ah);
    float sB = dt * Bv;
    h0 = fmaf(h0, dA, xh0 * sB);
    h1 = fmaf(h1, dA, xh1 * sB);
    float y0 = fmaf(h0, Cv, xh0 * Dh) * (z0 * fast_sigm(z0));
    float y1 = fmaf(h1, Cv, xh1 * Dh) * (z1 * fast_sigm(z1));
    unsigned int pk;
    asm("v_cvt_pk_bf16_f32 %0, %1, %2" : "=v"(pk) : "v"(y0), "v"(y1));
    int pD = Km + cbase, tD = Kd;
    if (pD >= 20480){ pD -= 20480; tD++; }
    if (dir) pD = 20479 - pD;
    ybuf[wbase + (unsigned int)tD * 1310720u + (unsigned int)pD * 64u] = pk;
  }
}

// ---------------- K3: fused epilogue, X1 in registers, loan2 via MFMA ----------------
__global__ __launch_bounds__(256) void k3_epi(
    const unsigned char* __restrict__ ws,
    const float* __restrict__ x, const float* __restrict__ xst,
    const int* __restrict__ curves,
    const float* __restrict__ b1, const float* __restrict__ b2,
    float* __restrict__ out)
{
  __shared__ unsigned short Abuf[2][64 * 128];   // [0]=yf-norm / t1 / gelu, [1]=yb-norm
  int tid = threadIdx.x; int lane = tid & 63; int w = tid >> 6;
  int pos0 = blockIdx.x * 64;
  int b = pos0 / (TT * PP); int rm = pos0 % (TT * PP);
  int t = rm / PP; int p0 = rm % PP;
  size_t tbase = (size_t)(b * TT + t) * PP;
  const int* cur = curves + b * PP;
  unsigned char* b0 = (unsigned char*)(&Abuf[0][0]);
  unsigned char* b1p = (unsigned char*)(&Abuf[1][0]);

  int colA = lane & 15, ag = lane >> 4;
  int crow0 = w * 16 + ag * 4;

  // ---- early gathered loads (residual x, xs A-frag) ----
  float xres[6][4];
  #pragma unroll
  for (int r2 = 0; r2 < 4; r2++){
    int cp = cur[p0 + crow0 + r2];
    const float* xr = x + (tbase + cp) * 96;
    #pragma unroll
    for (int nt = 0; nt < 6; nt++) xres[nt][r2] = xr[nt * 16 + colA];
  }
  union { unsigned short u[8]; short8 s; } al;
  {
    int arow = w * 16 + colA;
    int cpa = cur[p0 + arow];
    const float4* xsr = (const float4*)(xst + (tbase + cpa) * 8);
    float4 s0 = xsr[0], s1 = xsr[1];
    #pragma unroll
    for (int j = 0; j < 8; j++) al.u[j] = 0;
    if (ag == 0){
      al.u[0]=f2bf(s0.x); al.u[1]=f2bf(s0.y); al.u[2]=f2bf(s0.z); al.u[3]=f2bf(s0.w);
      al.u[4]=f2bf(s1.x); al.u[5]=f2bf(s1.y); al.u[6]=f2bf(s1.z); al.u[7]=f2bf(s1.w);
    } else if (ag == 1){ al.u[0] = 0x3F80u; }
  }

  // ---- stage 0: RMS-normalize yf,yb (nw & 0.5 folded into Wout frags) ----
  {
    int pp = tid >> 2, q = tid & 3;
    const u32x4* yfp = (const u32x4*)(ws + WS_YF) + (size_t)(pos0 + pp) * 16 + q * 4;
    const u32x4* ybp = (const u32x4*)(ws + WS_YB) + (size_t)(pos0 + pp) * 16 + q * 4;
    u32x4 fv[4], bv[4];
    #pragma unroll
    for (int j = 0; j < 4; j++){ fv[j] = yfp[j]; bv[j] = ybp[j]; }
    float ssf = 0.f, ssb = 0.f;
    #pragma unroll
    for (int j = 0; j < 4; j++){
      #pragma unroll
      for (int e = 0; e < 4; e++){
        unsigned int uf = fv[j][e], ub = bv[j][e];
        float a0 = asf(uf << 16), a1 = asf(uf & 0xffff0000u);
        float c0v = asf(ub << 16), c1v = asf(ub & 0xffff0000u);
        ssf += a0*a0 + a1*a1; ssb += c0v*c0v + c1v*c1v;
      }
    }
    ssf += __shfl_xor(ssf, 1); ssb += __shfl_xor(ssb, 1);
    ssf += __shfl_xor(ssf, 2); ssb += __shfl_xor(ssb, 2);
    float rf = __builtin_amdgcn_rsqf(ssf * (1.0f/128.0f) + EPSc);
    float rb = __builtin_amdgcn_rsqf(ssb * (1.0f/128.0f) + EPSc);
    #pragma unroll
    for (int j = 0; j < 4; j++){
      unsigned int pkf[4], pkb[4];
      #pragma unroll
      for (int e = 0; e < 4; e++){
        unsigned int uf = fv[j][e], ub = bv[j][e];
        float a0 = asf(uf << 16) * rf, a1 = asf(uf & 0xffff0000u) * rf;
        float c0v = asf(ub << 16) * rb, c1v = asf(ub & 0xffff0000u) * rb;
        asm("v_cvt_pk_bf16_f32 %0, %1, %2" : "=v"(pkf[e]) : "v"(a0), "v"(a1));
        asm("v_cvt_pk_bf16_f32 %0, %1, %2" : "=v"(pkb[e]) : "v"(c0v), "v"(c1v));
      }
      int off = pp * 256 + ((q * 64 + j * 16) ^ ((pp & 7) << 4));
      u32x4 sf = { pkf[0], pkf[1], pkf[2], pkf[3] };
      u32x4 sb = { pkb[0], pkb[1], pkb[2], pkb[3] };
      *(u32x4*)(b0 + off) = sf;
      *(u32x4*)(b1p + off) = sb;
    }
  }
  __syncthreads();

  // ---- stage 1: X1 = yf_n@Woutf + yb_n@Woutb + xg ; LN ; t1 = LN + tanh(loan2) ----
  f32x4 acc[6], accl[6];
  #pragma unroll
  for (int i = 0; i < 6; i++){ acc[i] = (f32x4){0.f,0.f,0.f,0.f}; accl[i] = (f32x4){0.f,0.f,0.f,0.f}; }
  {
    int arow = w * 16 + colA;
    unsigned int rmask = (unsigned int)((arow & 7) << 4);
    const short8* WF = (const short8*)(ws + WS_WOF);
    const short8* WB = (const short8*)(ws + WS_WOB);
    #pragma unroll
    for (int kk = 0; kk < 4; kk++){
      int offc = arow * 256 + (int)(((unsigned)(kk * 64 + ag * 16)) ^ rmask);
      short8 aff = *(const short8*)(b0 + offc);
      short8 abb = *(const short8*)(b1p + offc);
      #pragma unroll
      for (int nt = 0; nt < 6; nt++){
        acc[nt] = __builtin_amdgcn_mfma_f32_16x16x32_bf16(aff, WF[(nt*4+kk)*64 + lane], acc[nt], 0, 0, 0);
        acc[nt] = __builtin_amdgcn_mfma_f32_16x16x32_bf16(abb, WB[(nt*4+kk)*64 + lane], acc[nt], 0, 0, 0);
      }
    }
    const short8* WL = (const short8*)(ws + WS_L2);
    #pragma unroll
    for (int nt = 0; nt < 6; nt++)
      accl[nt] = __builtin_amdgcn_mfma_f32_16x16x32_bf16(al.s, WL[nt*64 + lane], accl[nt], 0, 0, 0);
  }
  float X1[6][4];
  #pragma unroll
  for (int nt = 0; nt < 6; nt++)
    #pragma unroll
    for (int r2 = 0; r2 < 4; r2++) X1[nt][r2] = acc[nt][r2] + xres[nt][r2];
  float mu[4], rsv[4];
  {
    float sA[4], sQ[4];
    #pragma unroll
    for (int r2 = 0; r2 < 4; r2++){
      float s = 0.f, s2 = 0.f;
      #pragma unroll
      for (int nt = 0; nt < 6; nt++){ float v = X1[nt][r2]; s += v; s2 += v * v; }
      sA[r2] = s; sQ[r2] = s2;
    }
    #pragma unroll
    for (int m = 1; m < 16; m <<= 1){
      #pragma unroll
      for (int r2 = 0; r2 < 4; r2++){ sA[r2] += __shfl_xor(sA[r2], m); sQ[r2] += __shfl_xor(sQ[r2], m); }
    }
    #pragma unroll
    for (int r2 = 0; r2 < 4; r2++){
      mu[r2] = sA[r2] * (1.0f / 96.0f);
      rsv[r2] = __builtin_amdgcn_rsqf(sQ[r2] * (1.0f / 96.0f) - mu[r2] * mu[r2] + EPSc);
    }
  }
  __syncthreads();   // all A1 reads done before overwrite
  #pragma unroll
  for (int nt = 0; nt < 6; nt++){
    #pragma unroll
    for (int r2 = 0; r2 < 4; r2++){
      float tv = (X1[nt][r2] - mu[r2]) * rsv[r2] + fast_tanh(accl[nt][r2]);
      int crow = crow0 + r2, n = nt * 16 + colA;
      *(unsigned short*)(b0 + crow * 256 + ((n * 2) ^ ((crow & 7) << 4))) = f2bf(tv);
    }
  }
  __syncthreads();

  // ---- stage 2: gelu(t1 @ W1 + b1) ----
  f32x4 acc2[6];
  #pragma unroll
  for (int i = 0; i < 6; i++) acc2[i] = (f32x4){0.f,0.f,0.f,0.f};
  {
    int arow = w * 16 + colA;
    unsigned int rmask = (unsigned int)((arow & 7) << 4);
    const short8* W1f = (const short8*)(ws + WS_W1);
    #pragma unroll
    for (int kk = 0; kk < 3; kk++){
      int offc = arow * 256 + (int)(((unsigned)(kk * 64 + ag * 16)) ^ rmask);
      short8 af = *(const short8*)(b0 + offc);
      #pragma unroll
      for (int nt = 0; nt < 6; nt++)
        acc2[nt] = __builtin_amdgcn_mfma_f32_16x16x32_bf16(af, W1f[(nt*3+kk)*64 + lane], acc2[nt], 0, 0, 0);
    }
  }
  float ge[6][4];
  #pragma unroll
  for (int nt = 0; nt < 6; nt++){
    float bv = b1[nt * 16 + colA];
    #pragma unroll
    for (int r2 = 0; r2 < 4; r2++) ge[nt][r2] = fast_gelu(acc2[nt][r2] + bv);
  }
  __syncthreads();
  #pragma unroll
  for (int nt = 0; nt < 6; nt++){
    #pragma unroll
    for (int r2 = 0; r2 < 4; r2++){
      int crow = crow0 + r2, n = nt * 16 + colA;
      *(unsigned short*)(b0 + crow * 256 + ((n * 2) ^ ((crow & 7) << 4))) = f2bf(ge[nt][r2]);
    }
  }
  __syncthreads();

  // ---- stage 3: out = gelu @ W2 + b2 + X1 ----
  f32x4 acc3[6];
  #pragma unroll
  for (int i = 0; i < 6; i++) acc3[i] = (f32x4){0.f,0.f,0.f,0.f};
  {
    int arow = w * 16 + colA;
    unsigned int rmask = (unsigned int)((arow & 7) << 4);
    const short8* W2f = (const short8*)(ws + WS_W2);
    #pragma unroll
    for (int kk = 0; kk < 3; kk++){
      int offc = arow * 256 + (int)(((unsigned)(kk * 64 + ag * 16)) ^ rmask);
      short8 af = *(const short8*)(b0 + offc);
      #pragma unroll
      for (int nt = 0; nt < 6; nt++)
        acc3[nt] = __builtin_amdgcn_mfma_f32_16x16x32_bf16(af, W2f[(nt*3+kk)*64 + lane], acc3[nt], 0, 0, 0);
    }
  }
  #pragma unroll
  for (int r2 = 0; r2 < 4; r2++){
    int crow = crow0 + r2;
    size_t ob = (tbase + p0 + crow) * 96;
    #pragma unroll
    for (int nt = 0; nt < 6; nt++){
      int n = nt * 16 + colA;
      out[ob + n] = acc3[nt][r2] + b2[n] + X1[nt][r2];
    }
  }
}

extern "C" void kernel_launch(void* const* d_in, const int* in_sizes, int n_in,
                              void* d_out, int out_size, void* d_ws, size_t ws_size,
                              hipStream_t stream)
{
  const float* x     = (const float*)d_in[0];
  const float* xst   = (const float*)d_in[1];
  const float* xhr   = (const float*)d_in[2];
  const int*   curves= (const int*)d_in[3];
  const float* embw  = (const float*)d_in[4];
  const float* embb  = (const float*)d_in[5];
  const float* l1w   = (const float*)d_in[6];
  const float* l1b   = (const float*)d_in[7];
  const float* l2w   = (const float*)d_in[8];
  const float* l2b   = (const float*)d_in[9];
  const float* winp  = (const float*)d_in[10];
  const float* cwf   = (const float*)d_in[11];
  const float* cbf   = (const float*)d_in[12];
  const float* dtbf  = (const float*)d_in[13];
  const float* alf   = (const float*)d_in[14];
  const float* Df    = (const float*)d_in[15];
  const float* nwf   = (const float*)d_in[16];
  const float* cwb   = (const float*)d_in[17];
  const float* cbb   = (const float*)d_in[18];
  const float* dtbb  = (const float*)d_in[19];
  const float* alb   = (const float*)d_in[20];
  const float* Db    = (const float*)d_in[21];
  const float* nwb   = (const float*)d_in[22];
  const float* wout  = (const float*)d_in[23];
  const float* w1    = (const float*)d_in[24];
  const float* b1    = (const float*)d_in[25];
  const float* w2    = (const float*)d_in[26];
  const float* b2    = (const float*)d_in[27];
  unsigned char* ws  = (unsigned char*)d_ws;

  k0_wprep<<<42, 256, 0, stream>>>(winp, wout, w1, w2, nwf, nwb,
                                   embw, embb, l1w, l1b, l2w, l2b, ws);
  k0b_inv<<<160, 256, 0, stream>>>(curves, ws);
  k1_prep<<<3840, 256, 0, stream>>>(x, xst, xhr, ws);
  k2_mamba<<<4096, 256, 0, stream>>>(ws, cwf, cbf, dtbf, alf, Df,
                                         cwb, cbb, dtbb, alb, Db);
  k3_epi<<<3840, 256, 0, stream>>>(ws, x, xst, curves, b1, b2, (float*)d_out);
}

// Round 7
// 432.211 us; speedup vs baseline: 2.0734x; 1.0536x over previous
//
#include <hip/hip_runtime.h>
#include <math.h>

typedef __attribute__((ext_vector_type(8))) short short8;
typedef __attribute__((ext_vector_type(4))) float f32x4;
typedef __attribute__((ext_vector_type(4))) unsigned int u32x4;

#define BB 2
#define TT 6
#define PP 20480
#define EPSc 1e-5f

// ws layout (bytes), all 16B aligned
#define WS_WIN   0u          // in_proj frags   [68][64] short8 = 69632
#define WS_WOF   69632u      // 0.5*nwf*Wout    [24][64] short8 = 24576
#define WS_WOB   94208u      // 0.5*nwb*Wout    [24][64] short8 = 24576
#define WS_W1    118784u     // mlp_w1 frags    [18][64] short8 = 18432
#define WS_W2    137216u     // mlp_w2 frags    [18][64] short8 = 18432
#define WS_EW    155648u     // embed frags(+eb row) [2][64] = 2048
#define WS_L1    157696u     // loan1 frags(+b row)  [8][64] = 8192
#define WS_L2    165888u     // loan2 frags(+b row)  [6][64] = 6144
#define WS_INV   172032u     // inverse perm int[2*20480] = 163840
#define WS_XN    335872u     // xn bf16 [245760][128] = 62914560
#define WS_YF    63250432u   // y_f bf16 (pre-norm) = 62914560
#define WS_YB    126164992u  // y_b bf16 (pre-norm, pre-flipped) = 62914560

__device__ __forceinline__ float asf(unsigned int u){ float f; __builtin_memcpy(&f, &u, 4); return f; }
__device__ __forceinline__ int f2i(float f){ int i; __builtin_memcpy(&i, &f, 4); return i; }
__device__ __forceinline__ unsigned short f2bf(float f){
  unsigned int u; __builtin_memcpy(&u, &f, 4);
  unsigned int r = (u + 0x7fffu + ((u >> 16) & 1u)) >> 16;
  return (unsigned short)r;
}
__device__ __forceinline__ float fast_sigm(float x){ return __builtin_amdgcn_rcpf(1.0f + __expf(-x)); }
__device__ __forceinline__ float fast_tanh(float x){ return 1.0f - 2.0f * __builtin_amdgcn_rcpf(1.0f + __expf(2.0f * x)); }
__device__ __forceinline__ float fast_gelu(float v){
  float s = v * 0.70710678118654752f;
  float ax = fabsf(s);
  float t = __builtin_amdgcn_rcpf(1.0f + 0.3275911f * ax);
  float p = t * (0.254829592f + t * (-0.284496736f + t * (1.421413741f + t * (-1.453152027f + t * 1.061405429f))));
  float er = 1.0f - p * __expf(-ax * ax);
  er = (s < 0.0f) ? -er : er;
  return 0.5f * v * (1.0f + er);
}

// ---------------- K0: all weight prep -> bf16 MFMA B-fragments ----------------
__global__ __launch_bounds__(256) void k0_wprep(
    const float* __restrict__ win, const float* __restrict__ wout,
    const float* __restrict__ w1m, const float* __restrict__ w2m,
    const float* __restrict__ nwf, const float* __restrict__ nwb,
    const float* __restrict__ ew, const float* __restrict__ eb,
    const float* __restrict__ l1w, const float* __restrict__ l1b,
    const float* __restrict__ l2w, const float* __restrict__ l2b,
    unsigned char* __restrict__ ws)
{
  int gt = blockIdx.x * 256 + threadIdx.x;
  int g = gt >> 6, lane = gt & 63;
  int ln = lane & 15, kg = lane >> 4;
  union { unsigned short u[8]; short8 s; } cv;
  unsigned int dst; int gl;
  if (g < 68){
    gl = g; int nt = gl >> 2, kk = gl & 3;
    int n = nt * 16 + ln;
    #pragma unroll
    for (int j = 0; j < 8; j++){
      int k = kk * 32 + kg * 8 + j;
      cv.u[j] = f2bf((n < 266) ? win[(size_t)k * 266 + n] : 0.0f);
    }
    dst = WS_WIN;
  } else if (g < 116){
    int isb = (g >= 92); gl = g - (isb ? 92 : 68);
    int nt = gl >> 2, kk = gl & 3;
    int n = nt * 16 + ln;
    const float* nw = isb ? nwb : nwf;
    #pragma unroll
    for (int j = 0; j < 8; j++){
      int k = kk * 32 + kg * 8 + j;
      cv.u[j] = f2bf(0.5f * nw[k] * wout[(size_t)k * 96 + n]);
    }
    dst = isb ? WS_WOB : WS_WOF;
  } else if (g < 152){
    int is2 = (g >= 134); gl = g - (is2 ? 134 : 116);
    int nt = gl / 3, kk = gl % 3;
    int n = nt * 16 + ln;
    const float* src = is2 ? w2m : w1m;
    #pragma unroll
    for (int j = 0; j < 8; j++){
      int k = kk * 32 + kg * 8 + j;
      cv.u[j] = f2bf(src[(size_t)k * 96 + n]);
    }
    dst = is2 ? WS_W2 : WS_W1;
  } else if (g < 154){
    gl = g - 152; int n = gl * 16 + ln;
    #pragma unroll
    for (int j = 0; j < 8; j++){
      int k = kg * 8 + j;
      float f = (k < 28) ? ew[k * 32 + n] : ((k == 28) ? eb[n] : 0.0f);
      cv.u[j] = f2bf(f);
    }
    dst = WS_EW;
  } else if (g < 162){
    gl = g - 154; int n = gl * 16 + ln;
    #pragma unroll
    for (int j = 0; j < 8; j++){
      int k = kg * 8 + j;
      float f = (k < 8) ? l1w[k * 128 + n] : ((k == 8) ? l1b[n] : 0.0f);
      cv.u[j] = f2bf(f);
    }
    dst = WS_L1;
  } else {
    gl = g - 162; int n = gl * 16 + ln;
    #pragma unroll
    for (int j = 0; j < 8; j++){
      int k = kg * 8 + j;
      float f = (k < 8) ? l2w[k * 96 + n] : ((k == 8) ? l2b[n] : 0.0f);
      cv.u[j] = f2bf(f);
    }
    dst = WS_L2;
  }
  *(short8*)(ws + dst + (size_t)(gl * 64 + lane) * 16) = cv.s;
}

// ---------------- K0b: inverse permutation ----------------
__global__ __launch_bounds__(256) void k0b_inv(
    const int* __restrict__ curves, unsigned char* __restrict__ ws)
{
  int i = blockIdx.x * 256 + threadIdx.x;   // < 40960
  int p = i % PP;
  ((int*)(ws + WS_INV))[(i / PP) * PP + curves[i]] = p;
}

// ---------------- K1: SOURCE-ordered gather-free prep ----------------
__global__ __launch_bounds__(256) void k1_prep(
    const float* __restrict__ x, const float* __restrict__ xst,
    const float* __restrict__ xhr, unsigned char* __restrict__ ws)
{
  __shared__ unsigned short hrl[4][16][40];    // tanh(embed), bf16
  __shared__ unsigned short lol[4][16][136];   // tanh(loan1), bf16
  int tid = threadIdx.x, lane = tid & 63, w = tid >> 6;
  int pos0 = blockIdx.x * 64;
  int b = pos0 / (TT * PP); int r = pos0 % (TT * PP);
  int t = r / PP; int c0 = r % PP;
  size_t tbase = (size_t)(b * TT + t) * PP;

  // ---- phase A ----
  {
    int arow = w * 16 + (lane & 15);
    int g = lane >> 4;
    const float* hrow = xhr + (tbase + c0 + arow) * 28;
    float4 f0 = *(const float4*)(hrow + g * 8);
    float4 f1 = (g < 3) ? *(const float4*)(hrow + g * 8 + 4) : (float4){0.f,0.f,0.f,0.f};
    const float4* xsr = (const float4*)(xst + (tbase + c0 + arow) * 8);
    float4 s0 = xsr[0], s1 = xsr[1];
    union { unsigned short u[8]; short8 s; } ae, al;
    ae.u[0]=f2bf(f0.x); ae.u[1]=f2bf(f0.y); ae.u[2]=f2bf(f0.z); ae.u[3]=f2bf(f0.w);
    ae.u[4]=f2bf(f1.x); ae.u[5]=f2bf(f1.y); ae.u[6]=f2bf(f1.z); ae.u[7]=f2bf(f1.w);
    if (g == 3){ ae.u[4] = 0x3F80u; ae.u[5]=0; ae.u[6]=0; ae.u[7]=0; }
    #pragma unroll
    for (int j = 0; j < 8; j++) al.u[j] = 0;
    if (g == 0){
      al.u[0]=f2bf(s0.x); al.u[1]=f2bf(s0.y); al.u[2]=f2bf(s0.z); al.u[3]=f2bf(s0.w);
      al.u[4]=f2bf(s1.x); al.u[5]=f2bf(s1.y); al.u[6]=f2bf(s1.z); al.u[7]=f2bf(s1.w);
    } else if (g == 1){ al.u[0] = 0x3F80u; }
    const short8* BE = (const short8*)(ws + WS_EW);
    const short8* BL = (const short8*)(ws + WS_L1);
    f32x4 he0 = {0.f,0.f,0.f,0.f}, he1 = {0.f,0.f,0.f,0.f};
    he0 = __builtin_amdgcn_mfma_f32_16x16x32_bf16(ae.s, BE[lane], he0, 0, 0, 0);
    he1 = __builtin_amdgcn_mfma_f32_16x16x32_bf16(ae.s, BE[64 + lane], he1, 0, 0, 0);
    f32x4 lo[8];
    #pragma unroll
    for (int nt = 0; nt < 8; nt++){
      f32x4 z = {0.f,0.f,0.f,0.f};
      lo[nt] = __builtin_amdgcn_mfma_f32_16x16x32_bf16(al.s, BL[nt * 64 + lane], z, 0, 0, 0);
    }
    int rl = (lane >> 4) * 4, col = lane & 15;
    #pragma unroll
    for (int r2 = 0; r2 < 4; r2++){
      hrl[w][rl + r2][col]      = f2bf(fast_tanh(he0[r2]));
      hrl[w][rl + r2][16 + col] = f2bf(fast_tanh(he1[r2]));
    }
    #pragma unroll
    for (int nt = 0; nt < 8; nt++){
      #pragma unroll
      for (int r2 = 0; r2 < 4; r2++)
        lol[w][rl + r2][nt * 16 + col] = f2bf(fast_tanh(lo[nt][r2]));
    }
  }
  __syncthreads();

  // ---- phase B ----
  int pp = tid >> 2, q = tid & 3;
  int c = c0 + pp;
  union { float4 v4[8]; float v[32]; } xv;
  if (q < 3){
    const float4* xr4 = (const float4*)(x + (tbase + c) * 96 + q * 32);
    #pragma unroll
    for (int j = 0; j < 8; j++) xv.v4[j] = xr4[j];
  } else {
    const u32x4* hp = (const u32x4*)(&hrl[pp >> 4][pp & 15][0]);
    #pragma unroll
    for (int j = 0; j < 4; j++){
      u32x4 hv = hp[j];
      #pragma unroll
      for (int e = 0; e < 4; e++){
        unsigned int u = hv[e];
        xv.v[j*8 + e*2]     = asf(u << 16);
        xv.v[j*8 + e*2 + 1] = asf(u & 0xffff0000u);
      }
    }
  }
  float s = 0.f, s2 = 0.f;
  #pragma unroll
  for (int j = 0; j < 32; j++){ float v = xv.v[j]; s += v; s2 += v * v; }
  s += __shfl_xor(s, 1); s2 += __shfl_xor(s2, 1);
  s += __shfl_xor(s, 2); s2 += __shfl_xor(s2, 2);
  float mu = s * (1.0f / 128.0f);
  float rs = __builtin_amdgcn_rsqf(s2 * (1.0f / 128.0f) - mu * mu + EPSc);

  int p = ((const int*)(ws + WS_INV))[b * PP + c];
  const u32x4* lp = (const u32x4*)(&lol[pp >> 4][pp & 15][q * 32]);
  u32x4* dst = (u32x4*)((unsigned short*)(ws + WS_XN) + (tbase + p) * 128 + q * 32);
  #pragma unroll
  for (int j = 0; j < 4; j++){
    u32x4 lv = lp[j];
    unsigned int pk[4];
    #pragma unroll
    for (int e = 0; e < 4; e++){
      unsigned int lu = lv[e];
      float l0 = asf(lu << 16), l1 = asf(lu & 0xffff0000u);
      int idx = j*8 + e*2;
      float r0 = (xv.v[idx]   - mu) * rs + l0;
      float r1 = (xv.v[idx+1] - mu) * rs + l1;
      asm("v_cvt_pk_bf16_f32 %0, %1, %2" : "=v"(pk[e]) : "v"(r0), "v"(r1));
    }
    u32x4 stv = { pk[0], pk[1], pk[2], pk[3] };
    dst[j] = stv;
  }
}

// row index within the tile for scan step s (bwd reads reversed cells)
__device__ __forceinline__ int urow_of(int s, int dir){
  int g0 = (s >= 20) ? 2 : ((s >= 10) ? 1 : 0);
  int g1 = s - g0 * 10;
  return dir ? (g0 * 10 + 9 - g1) : s;
}

// ---------------- K2: fused in_proj MFMA + bidirectional Mamba scan ----------------
// 256 threads = 4 waves = 2 window-pairs. pair = wid>>1, dir = wid&1.
// Scan coefficients (dA, sB, Cv) precomputed once per wave (lane-parallel over (l,h)),
// fetched in the scan via ds_bpermute / readlane.
#define ULDS 276   // row stride in u16 (552 B = 138 dwords, 138%32=10 -> conflict-free group shift)
__global__ __launch_bounds__(256, 4) void k2_mamba(
    unsigned char* __restrict__ ws,
    const float* __restrict__ cwf, const float* __restrict__ cbf,
    const float* __restrict__ dtbf, const float* __restrict__ alf,
    const float* __restrict__ Dpf,
    const float* __restrict__ cwb, const float* __restrict__ cbb,
    const float* __restrict__ dtbb, const float* __restrict__ alb,
    const float* __restrict__ Dpb)
{
  __shared__ unsigned short uld[2][30][ULDS];
  int blk = blockIdx.x;
  int b = blk >> 11; int tb = (blk >> 10) & 1; int pbh = blk & 1023;
  int wid = threadIdx.x >> 6, lane = threadIdx.x & 63;
  int pairIdx = wid >> 1, dir = wid & 1;
  int pb = pbh * 2 + pairIdx;

  // --- phase 1: u = xn @ W_in via MFMA ---
  const unsigned short* xn = (const unsigned short*)(ws + WS_XN);
  int lr = dir * 16 + (lane & 15); if (lr > 29) lr = 29;
  int g0r = lr / 10, g1r = lr - g0r * 10;
  const unsigned short* arow = xn + (((size_t)(b * TT + tb * 3 + g0r) * PP) + (size_t)pb * 10 + g1r) * 128 + (lane >> 4) * 8;
  short8 afr[4];
  #pragma unroll
  for (int kk = 0; kk < 4; kk++) afr[kk] = *(const short8*)(arow + kk * 32);
  const short8* bbm = (const short8*)(ws + WS_WIN);
  int row0 = dir * 16 + (lane >> 4) * 4;
  int col0 = lane & 15;
  #pragma unroll
  for (int half = 0; half < 2; half++){
    const int n0 = half ? 9 : 0;
    const int cnt = half ? 8 : 9;
    f32x4 acc[9];
    #pragma unroll
    for (int i = 0; i < 9; i++) acc[i] = (f32x4){0.f,0.f,0.f,0.f};
    #pragma unroll
    for (int kk = 0; kk < 4; kk++){
      #pragma unroll
      for (int j = 0; j < 9; j++){
        if (j < cnt){
          short8 bf = bbm[((n0 + j) * 4 + kk) * 64 + lane];
          acc[j] = __builtin_amdgcn_mfma_f32_16x16x32_bf16(afr[kk], bf, acc[j], 0, 0, 0);
        }
      }
    }
    #pragma unroll
    for (int j = 0; j < 9; j++){
      if (j < cnt){
        int col = (n0 + j) * 16 + col0;
        #pragma unroll
        for (int r2 = 0; r2 < 4; r2++){
          int row = row0 + r2;
          if (row < 30 && col < 266) uld[pairIdx][row][col] = f2bf(acc[j][r2]);
        }
      }
    }
  }
  __syncthreads();

  // --- per-direction parameters ---
  const float* cw  = dir ? cwb  : cwf;
  const float* cb  = dir ? cbb  : cbf;
  const float* dtb = dir ? dtbb : dtbf;
  const float* al  = dir ? alb  : alf;
  const float* Dp  = dir ? Dpb  : Dpf;
  unsigned int* ybuf = (unsigned int*)(ws + (dir ? WS_YB : WS_YF));
  int pbown = dir ? (2047 - pb) : pb;
  int cbase = (tb * 1024 + (pbown >> 1)) * 6 + (pbown & 1);
  unsigned int wbase = (unsigned int)b * 7864320u + (unsigned int)lane;
  const unsigned short* tile = &uld[pairIdx][0][0];

  int c0 = lane * 2;
  int hh = lane >> 3;
  float w00=cw[c0*3+0], w01=cw[c0*3+1], w02=cw[c0*3+2], cb0=cb[c0];
  float w10=cw[c0*3+3], w11=cw[c0*3+4], w12=cw[c0*3+5], cb1=cb[c0+1];
  float wB0=cw[128*3+0], wB1=cw[128*3+1], wB2=cw[128*3+2], cbB=cb[128];
  float wC0=cw[129*3+0], wC1=cw[129*3+1], wC2=cw[129*3+2], cbC=cb[129];
  float Dh = Dp[hh];

  // --- phase 2a: precompute dA(l,h), sB(l,h), Cv(l) ---
  // chunk c: this lane handles l = c*8 + (lane>>3), h = lane&7
  float dAc[4], sBc[4], Cvc[4];
  {
    int h2 = lane & 7;
    int lrow = lane >> 3;
    float dtb2 = dtb[h2];
    float Ah2 = -__expf(al[h2]);
    #pragma unroll
    for (int cci = 0; cci < 4; cci++){
      int l = cci * 8 + lrow; if (l > 29) l = 29;
      float Braw[3], Craw[3];
      #pragma unroll
      for (int tap = 0; tap < 3; tap++){
        int sp = l - tap;
        if (sp >= 0){
          unsigned int wv = *(const unsigned int*)(tile + urow_of(sp, dir) * ULDS + 256);
          Braw[tap] = asf(wv << 16);
          Craw[tap] = asf(wv & 0xffff0000u);
        } else { Braw[tap] = 0.f; Craw[tap] = 0.f; }
      }
      float Bcc = fmaf(wB2, Braw[0], fmaf(wB1, Braw[1], fmaf(wB0, Braw[2], cbB)));
      float Ccc = fmaf(wC2, Craw[0], fmaf(wC1, Craw[1], fmaf(wC0, Craw[2], cbC)));
      float Bvv = Bcc * fast_sigm(Bcc);
      Cvc[cci]  = Ccc * fast_sigm(Ccc);
      float dtr = asf((unsigned int)tile[urow_of(l, dir) * ULDS + 258 + h2] << 16);
      float dtx = dtr + dtb2;
      float e = __expf(-fabsf(dtx));
      float dt = fmaxf(dtx, 0.0f) + __logf(1.0f + e);
      dAc[cci] = __expf(dt * Ah2);
      sBc[cci] = dt * Bvv;
    }
  }

  // --- phase 2b: scan ---
  int vbase = (lane >> 3) << 2;   // bpermute lane-group base (bytes)
  float xp10=0,xp20=0,xp11=0,xp21=0;
  float h0=0.f, h1=0.f;
  #pragma unroll
  for (int l = 0; l < 30; l++){
    const int Kl = (l/3)*12288 + (l%3)*2;
    const int Kd = Kl / 20480, Km = Kl % 20480;
    const int urow_b = (l/10)*10 + 9 - (l%10);
    const unsigned short* ur = tile + (dir ? urow_b : l) * ULDS;
    unsigned int zz = *(const unsigned int*)(ur + c0);
    unsigned int xx = *(const unsigned int*)(ur + 128 + c0);
    const int chn = l >> 3, rrl = l & 7;
    float dA = asf((unsigned int)__builtin_amdgcn_ds_bpermute(vbase + (rrl << 5), f2i(dAc[chn])));
    float sB = asf((unsigned int)__builtin_amdgcn_ds_bpermute(vbase + (rrl << 5), f2i(sBc[chn])));
    float Cv = asf((unsigned int)__builtin_amdgcn_readlane(f2i(Cvc[chn]), rrl * 8));
    float z0 = asf(zz << 16), z1 = asf(zz & 0xffff0000u);
    float xr0 = asf(xx << 16), xr1 = asf(xx & 0xffff0000u);
    float xc0 = fmaf(w02, xr0, fmaf(w01, xp10, fmaf(w00, xp20, cb0)));
    float xc1 = fmaf(w12, xr1, fmaf(w11, xp11, fmaf(w10, xp21, cb1)));
    xp20=xp10; xp10=xr0; xp21=xp11; xp11=xr1;
    float xh0 = xc0 * fast_sigm(xc0), xh1 = xc1 * fast_sigm(xc1);
    h0 = fmaf(h0, dA, xh0 * sB);
    h1 = fmaf(h1, dA, xh1 * sB);
    float y0 = fmaf(h0, Cv, xh0 * Dh) * (z0 * fast_sigm(z0));
    float y1 = fmaf(h1, Cv, xh1 * Dh) * (z1 * fast_sigm(z1));
    unsigned int pk;
    asm("v_cvt_pk_bf16_f32 %0, %1, %2" : "=v"(pk) : "v"(y0), "v"(y1));
    int pD = Km + cbase, tD = Kd;
    if (pD >= 20480){ pD -= 20480; tD++; }
    if (dir) pD = 20479 - pD;
    ybuf[wbase + (unsigned int)tD * 1310720u + (unsigned int)pD * 64u] = pk;
  }
}

// ---------------- K3: fused epilogue, X1 in registers, loan2 via MFMA ----------------
__global__ __launch_bounds__(256) void k3_epi(
    const unsigned char* __restrict__ ws,
    const float* __restrict__ x, const float* __restrict__ xst,
    const int* __restrict__ curves,
    const float* __restrict__ b1, const float* __restrict__ b2,
    float* __restrict__ out)
{
  __shared__ unsigned short Abuf[2][64 * 128];   // [0]=yf-norm / t1 / gelu, [1]=yb-norm
  int tid = threadIdx.x; int lane = tid & 63; int w = tid >> 6;
  int pos0 = blockIdx.x * 64;
  int b = pos0 / (TT * PP); int rm = pos0 % (TT * PP);
  int t = rm / PP; int p0 = rm % PP;
  size_t tbase = (size_t)(b * TT + t) * PP;
  const int* cur = curves + b * PP;
  unsigned char* b0 = (unsigned char*)(&Abuf[0][0]);
  unsigned char* b1p = (unsigned char*)(&Abuf[1][0]);

  int colA = lane & 15, ag = lane >> 4;
  int crow0 = w * 16 + ag * 4;

  // ---- early gathered loads (residual x, xs A-frag) ----
  float xres[6][4];
  #pragma unroll
  for (int r2 = 0; r2 < 4; r2++){
    int cp = cur[p0 + crow0 + r2];
    const float* xr = x + (tbase + cp) * 96;
    #pragma unroll
    for (int nt = 0; nt < 6; nt++) xres[nt][r2] = xr[nt * 16 + colA];
  }
  union { unsigned short u[8]; short8 s; } al;
  {
    int arow = w * 16 + colA;
    int cpa = cur[p0 + arow];
    const float4* xsr = (const float4*)(xst + (tbase + cpa) * 8);
    float4 s0 = xsr[0], s1 = xsr[1];
    #pragma unroll
    for (int j = 0; j < 8; j++) al.u[j] = 0;
    if (ag == 0){
      al.u[0]=f2bf(s0.x); al.u[1]=f2bf(s0.y); al.u[2]=f2bf(s0.z); al.u[3]=f2bf(s0.w);
      al.u[4]=f2bf(s1.x); al.u[5]=f2bf(s1.y); al.u[6]=f2bf(s1.z); al.u[7]=f2bf(s1.w);
    } else if (ag == 1){ al.u[0] = 0x3F80u; }
  }

  // ---- stage 0: RMS-normalize yf,yb (nw & 0.5 folded into Wout frags) ----
  {
    int pp = tid >> 2, q = tid & 3;
    const u32x4* yfp = (const u32x4*)(ws + WS_YF) + (size_t)(pos0 + pp) * 16 + q * 4;
    const u32x4* ybp = (const u32x4*)(ws + WS_YB) + (size_t)(pos0 + pp) * 16 + q * 4;
    u32x4 fv[4], bv[4];
    #pragma unroll
    for (int j = 0; j < 4; j++){ fv[j] = yfp[j]; bv[j] = ybp[j]; }
    float ssf = 0.f, ssb = 0.f;
    #pragma unroll
    for (int j = 0; j < 4; j++){
      #pragma unroll
      for (int e = 0; e < 4; e++){
        unsigned int uf = fv[j][e], ub = bv[j][e];
        float a0 = asf(uf << 16), a1 = asf(uf & 0xffff0000u);
        float c0v = asf(ub << 16), c1v = asf(ub & 0xffff0000u);
        ssf += a0*a0 + a1*a1; ssb += c0v*c0v + c1v*c1v;
      }
    }
    ssf += __shfl_xor(ssf, 1); ssb += __shfl_xor(ssb, 1);
    ssf += __shfl_xor(ssf, 2); ssb += __shfl_xor(ssb, 2);
    float rf = __builtin_amdgcn_rsqf(ssf * (1.0f/128.0f) + EPSc);
    float rb = __builtin_amdgcn_rsqf(ssb * (1.0f/128.0f) + EPSc);
    #pragma unroll
    for (int j = 0; j < 4; j++){
      unsigned int pkf[4], pkb[4];
      #pragma unroll
      for (int e = 0; e < 4; e++){
        unsigned int uf = fv[j][e], ub = bv[j][e];
        float a0 = asf(uf << 16) * rf, a1 = asf(uf & 0xffff0000u) * rf;
        float c0v = asf(ub << 16) * rb, c1v = asf(ub & 0xffff0000u) * rb;
        asm("v_cvt_pk_bf16_f32 %0, %1, %2" : "=v"(pkf[e]) : "v"(a0), "v"(a1));
        asm("v_cvt_pk_bf16_f32 %0, %1, %2" : "=v"(pkb[e]) : "v"(c0v), "v"(c1v));
      }
      int off = pp * 256 + ((q * 64 + j * 16) ^ ((pp & 7) << 4));
      u32x4 sf = { pkf[0], pkf[1], pkf[2], pkf[3] };
      u32x4 sb = { pkb[0], pkb[1], pkb[2], pkb[3] };
      *(u32x4*)(b0 + off) = sf;
      *(u32x4*)(b1p + off) = sb;
    }
  }
  __syncthreads();

  // ---- stage 1: X1 = yf_n@Woutf + yb_n@Woutb + xg ; LN ; t1 = LN + tanh(loan2) ----
  f32x4 acc[6], accl[6];
  #pragma unroll
  for (int i = 0; i < 6; i++){ acc[i] = (f32x4){0.f,0.f,0.f,0.f}; accl[i] = (f32x4){0.f,0.f,0.f,0.f}; }
  {
    int arow = w * 16 + colA;
    unsigned int rmask = (unsigned int)((arow & 7) << 4);
    const short8* WF = (const short8*)(ws + WS_WOF);
    const short8* WB = (const short8*)(ws + WS_WOB);
    #pragma unroll
    for (int kk = 0; kk < 4; kk++){
      int offc = arow * 256 + (int)(((unsigned)(kk * 64 + ag * 16)) ^ rmask);
      short8 aff = *(const short8*)(b0 + offc);
      short8 abb = *(const short8*)(b1p + offc);
      #pragma unroll
      for (int nt = 0; nt < 6; nt++){
        acc[nt] = __builtin_amdgcn_mfma_f32_16x16x32_bf16(aff, WF[(nt*4+kk)*64 + lane], acc[nt], 0, 0, 0);
        acc[nt] = __builtin_amdgcn_mfma_f32_16x16x32_bf16(abb, WB[(nt*4+kk)*64 + lane], acc[nt], 0, 0, 0);
      }
    }
    const short8* WL = (const short8*)(ws + WS_L2);
    #pragma unroll
    for (int nt = 0; nt < 6; nt++)
      accl[nt] = __builtin_amdgcn_mfma_f32_16x16x32_bf16(al.s, WL[nt*64 + lane], accl[nt], 0, 0, 0);
  }
  float X1[6][4];
  #pragma unroll
  for (int nt = 0; nt < 6; nt++)
    #pragma unroll
    for (int r2 = 0; r2 < 4; r2++) X1[nt][r2] = acc[nt][r2] + xres[nt][r2];
  float mu[4], rsv[4];
  {
    float sA[4], sQ[4];
    #pragma unroll
    for (int r2 = 0; r2 < 4; r2++){
      float s = 0.f, s2 = 0.f;
      #pragma unroll
      for (int nt = 0; nt < 6; nt++){ float v = X1[nt][r2]; s += v; s2 += v * v; }
      sA[r2] = s; sQ[r2] = s2;
    }
    #pragma unroll
    for (int m = 1; m < 16; m <<= 1){
      #pragma unroll
      for (int r2 = 0; r2 < 4; r2++){ sA[r2] += __shfl_xor(sA[r2], m); sQ[r2] += __shfl_xor(sQ[r2], m); }
    }
    #pragma unroll
    for (int r2 = 0; r2 < 4; r2++){
      mu[r2] = sA[r2] * (1.0f / 96.0f);
      rsv[r2] = __builtin_amdgcn_rsqf(sQ[r2] * (1.0f / 96.0f) - mu[r2] * mu[r2] + EPSc);
    }
  }
  __syncthreads();   // all A1 reads done before overwrite
  #pragma unroll
  for (int nt = 0; nt < 6; nt++){
    #pragma unroll
    for (int r2 = 0; r2 < 4; r2++){
      float tv = (X1[nt][r2] - mu[r2]) * rsv[r2] + fast_tanh(accl[nt][r2]);
      int crow = crow0 + r2, n = nt * 16 + colA;
      *(unsigned short*)(b0 + crow * 256 + ((n * 2) ^ ((crow & 7) << 4))) = f2bf(tv);
    }
  }
  __syncthreads();

  // ---- stage 2: gelu(t1 @ W1 + b1) ----
  f32x4 acc2[6];
  #pragma unroll
  for (int i = 0; i < 6; i++) acc2[i] = (f32x4){0.f,0.f,0.f,0.f};
  {
    int arow = w * 16 + colA;
    unsigned int rmask = (unsigned int)((arow & 7) << 4);
    const short8* W1f = (const short8*)(ws + WS_W1);
    #pragma unroll
    for (int kk = 0; kk < 3; kk++){
      int offc = arow * 256 + (int)(((unsigned)(kk * 64 + ag * 16)) ^ rmask);
      short8 af = *(const short8*)(b0 + offc);
      #pragma unroll
      for (int nt = 0; nt < 6; nt++)
        acc2[nt] = __builtin_amdgcn_mfma_f32_16x16x32_bf16(af, W1f[(nt*3+kk)*64 + lane], acc2[nt], 0, 0, 0);
    }
  }
  float ge[6][4];
  #pragma unroll
  for (int nt = 0; nt < 6; nt++){
    float bv = b1[nt * 16 + colA];
    #pragma unroll
    for (int r2 = 0; r2 < 4; r2++) ge[nt][r2] = fast_gelu(acc2[nt][r2] + bv);
  }
  __syncthreads();
  #pragma unroll
  for (int nt = 0; nt < 6; nt++){
    #pragma unroll
    for (int r2 = 0; r2 < 4; r2++){
      int crow = crow0 + r2, n = nt * 16 + colA;
      *(unsigned short*)(b0 + crow * 256 + ((n * 2) ^ ((crow & 7) << 4))) = f2bf(ge[nt][r2]);
    }
  }
  __syncthreads();

  // ---- stage 3: out = gelu @ W2 + b2 + X1 ----
  f32x4 acc3[6];
  #pragma unroll
  for (int i = 0; i < 6; i++) acc3[i] = (f32x4){0.f,0.f,0.f,0.f};
  {
    int arow = w * 16 + colA;
    unsigned int rmask = (unsigned int)((arow & 7) << 4);
    const short8* W2f = (const short8*)(ws + WS_W2);
    #pragma unroll
    for (int kk = 0; kk < 3; kk++){
      int offc = arow * 256 + (int)(((unsigned)(kk * 64 + ag * 16)) ^ rmask);
      short8 af = *(const short8*)(b0 + offc);
      #pragma unroll
      for (int nt = 0; nt < 6; nt++)
        acc3[nt] = __builtin_amdgcn_mfma_f32_16x16x32_bf16(af, W2f[(nt*3+kk)*64 + lane], acc3[nt], 0, 0, 0);
    }
  }
  #pragma unroll
  for (int r2 = 0; r2 < 4; r2++){
    int crow = crow0 + r2;
    size_t ob = (tbase + p0 + crow) * 96;
    #pragma unroll
    for (int nt = 0; nt < 6; nt++){
      int n = nt * 16 + colA;
      out[ob + n] = acc3[nt][r2] + b2[n] + X1[nt][r2];
    }
  }
}

extern "C" void kernel_launch(void* const* d_in, const int* in_sizes, int n_in,
                              void* d_out, int out_size, void* d_ws, size_t ws_size,
                              hipStream_t stream)
{
  const float* x     = (const float*)d_in[0];
  const float* xst   = (const float*)d_in[1];
  const float* xhr   = (const float*)d_in[2];
  const int*   curves= (const int*)d_in[3];
  const float* embw  = (const float*)d_in[4];
  const float* embb  = (const float*)d_in[5];
  const float* l1w   = (const float*)d_in[6];
  const float* l1b   = (const float*)d_in[7];
  const float* l2w   = (const float*)d_in[8];
  const float* l2b   = (const float*)d_in[9];
  const float* winp  = (const float*)d_in[10];
  const float* cwf   = (const float*)d_in[11];
  const float* cbf   = (const float*)d_in[12];
  const float* dtbf  = (const float*)d_in[13];
  const float* alf   = (const float*)d_in[14];
  const float* Df    = (const float*)d_in[15];
  const float* nwf   = (const float*)d_in[16];
  const float* cwb   = (const float*)d_in[17];
  const float* cbb   = (const float*)d_in[18];
  const float* dtbb  = (const float*)d_in[19];
  const float* alb   = (const float*)d_in[20];
  const float* Db    = (const float*)d_in[21];
  const float* nwb   = (const float*)d_in[22];
  const float* wout  = (const float*)d_in[23];
  const float* w1    = (const float*)d_in[24];
  const float* b1    = (const float*)d_in[25];
  const float* w2    = (const float*)d_in[26];
  const float* b2    = (const float*)d_in[27];
  unsigned char* ws  = (unsigned char*)d_ws;

  k0_wprep<<<42, 256, 0, stream>>>(winp, wout, w1, w2, nwf, nwb,
                                   embw, embb, l1w, l1b, l2w, l2b, ws);
  k0b_inv<<<160, 256, 0, stream>>>(curves, ws);
  k1_prep<<<3840, 256, 0, stream>>>(x, xst, xhr, ws);
  k2_mamba<<<4096, 256, 0, stream>>>(ws, cwf, cbf, dtbf, alf, Df,
                                         cwb, cbb, dtbb, alb, Db);
  k3_epi<<<3840, 256, 0, stream>>>(ws, x, xst, curves, b1, b2, (float*)d_out);
}